// Round 1
// baseline (3921.094 us; speedup 1.0000x reference)
//
#include <hip/hip_runtime.h>
#include <math.h>

#define XD 100
#define HD 64
#define GD 192
#define TL 15
#define NHEADS 4
#define OUTD 32

__device__ __forceinline__ float sigmoidf_(float x) { return 1.0f / (1.0f + expf(-x)); }

// ---------------- TreeLSTM: one CFG node (16 AST nodes) per block ----------------
__global__ __launch_bounds__(256) void treelstm_kernel(
    const float* __restrict__ ast_x, const float* __restrict__ c_init,
    const float* __restrict__ W_iou, const float* __restrict__ b_iou,
    const float* __restrict__ U_iou, const float* __restrict__ U_f_W,
    const float* __restrict__ U_f_b, float* __restrict__ h_root)
{
    __shared__ float xs[TL][XD];        // 6 KB
    __shared__ float iou[TL][GD];       // 11.5 KB
    __shared__ float c_leaf[TL][HD];
    __shared__ float h_leaf[TL][HD];
    __shared__ float h_tild[HD];
    __shared__ float c_red_p[4][HD];
    __shared__ float iour[GD];

    const int n = blockIdx.x;
    const int tid = threadIdx.x;

    // leaves are rows n*16+1 .. n*16+15: contiguous 1500 floats
    const float* xb = ast_x + ((size_t)n * 16 + 1) * XD;
    for (int i = tid; i < TL * XD; i += 256) ((float*)xs)[i] = xb[i];
    __syncthreads();

    // iou_l = x_leaf @ W_iou.T + b_iou   (15x192 dots of length 100)
    for (int idx = tid; idx < TL * GD; idx += 256) {
        const int t = idx / GD, g = idx - t * GD;
        const float* wr = W_iou + g * XD;
        float acc = b_iou[g];
        #pragma unroll 4
        for (int k = 0; k < XD; ++k) acc = fmaf(xs[t][k], wr[k], acc);
        iou[t][g] = acc;
    }
    __syncthreads();

    // c_leaf = sig(i)*tanh(u) + c_init ; h_leaf = sig(o)*tanh(c_leaf)
    const float* cb = c_init + ((size_t)n * 16 + 1) * HD;
    for (int idx = tid; idx < TL * HD; idx += 256) {
        const int t = idx >> 6, h = idx & 63;
        float c = sigmoidf_(iou[t][h]) * tanhf(iou[t][h + 128]) + cb[idx];
        c_leaf[t][h] = c;
        h_leaf[t][h] = sigmoidf_(iou[t][h + 64]) * tanhf(c);
    }
    __syncthreads();

    // h_tild = sum_t h_leaf
    if (tid < HD) {
        float s = 0.f;
        #pragma unroll
        for (int t = 0; t < TL; ++t) s += h_leaf[t][tid];
        h_tild[tid] = s;
    }
    // forget gates + c_red partials (4 groups of leaves)
    {
        const int h = tid & 63, t0 = tid >> 6;
        float local = 0.f;
        for (int t = t0; t < TL; t += 4) {
            float acc = U_f_b[h];
            #pragma unroll 4
            for (int k = 0; k < HD; ++k) acc = fmaf(h_leaf[t][k], U_f_W[h * HD + k], acc);
            local += sigmoidf_(acc) * c_leaf[t][h];
        }
        c_red_p[t0][h] = local;
    }
    __syncthreads();

    // iou_r = h_tild @ U_iou.T + b_iou
    if (tid < GD) {
        float acc = b_iou[tid];
        #pragma unroll 4
        for (int k = 0; k < HD; ++k) acc = fmaf(h_tild[k], U_iou[tid * HD + k], acc);
        iour[tid] = acc;
    }
    __syncthreads();

    if (tid < HD) {
        float cred = (c_red_p[0][tid] + c_red_p[1][tid]) + (c_red_p[2][tid] + c_red_p[3][tid]);
        float c = sigmoidf_(iour[tid]) * tanhf(iour[tid + 128]) + cred;
        h_root[(size_t)n * HD + tid] = sigmoidf_(iour[tid + 64]) * tanhf(c);
    }
}

// ---------------- feat = cfg_type@Wt.T ; fsrc = feat@Wfc.T ; el/er ----------------
__global__ __launch_bounds__(128) void featatt_kernel(
    const float* __restrict__ cfg_type, const float* __restrict__ Wt,
    const float* __restrict__ Wfc, const float* __restrict__ attn_l,
    const float* __restrict__ attn_r, float* __restrict__ el, float* __restrict__ er)
{
    __shared__ float xt[XD];
    __shared__ float feat[HD];
    __shared__ float fsrc[NHEADS * OUTD];
    const int n = blockIdx.x, tid = threadIdx.x;
    if (tid < XD) xt[tid] = cfg_type[(size_t)n * XD + tid];
    __syncthreads();
    if (tid < HD) {
        float acc = 0.f;
        #pragma unroll 4
        for (int k = 0; k < XD; ++k) acc = fmaf(xt[k], Wt[tid * XD + k], acc);
        feat[tid] = acc;
    }
    __syncthreads();
    {
        float acc = 0.f;
        #pragma unroll 4
        for (int k = 0; k < HD; ++k) acc = fmaf(feat[k], Wfc[tid * HD + k], acc);
        fsrc[tid] = acc;
    }
    __syncthreads();
    if (tid < 8) {
        const int h = tid & 3;
        const float* attn = (tid < 4) ? attn_l : attn_r;
        float s = 0.f;
        #pragma unroll
        for (int o = 0; o < OUTD; ++o) s += fsrc[h * OUTD + o] * attn[h * OUTD + o];
        ((tid < 4) ? el : er)[(size_t)n * NHEADS + h] = s;
    }
}

// ---------------- CSR build ----------------
__global__ void zero_int(int* __restrict__ p, int n) {
    int i = blockIdx.x * blockDim.x + threadIdx.x;
    if (i < n) p[i] = 0;
}

__global__ void count_kernel(const int* __restrict__ dst, int* __restrict__ cnt, int E) {
    for (int e = blockIdx.x * blockDim.x + threadIdx.x; e < E; e += gridDim.x * blockDim.x)
        atomicAdd(&cnt[dst[e]], 1);
}

__global__ __launch_bounds__(1024) void scan_kernel(
    const int* __restrict__ cnt, int* __restrict__ offs, int* __restrict__ cursor, int N)
{
    __shared__ int part[1024];
    const int tid = threadIdx.x;
    const int per = (N + 1023) >> 10;
    int begin = tid * per;
    int end = begin + per; if (end > N) end = N;
    int s = 0;
    for (int i = begin; i < end && i < N; ++i) s += cnt[i];
    part[tid] = s;
    __syncthreads();
    for (int off = 1; off < 1024; off <<= 1) {
        int t = (tid >= off) ? part[tid - off] : 0;
        __syncthreads();
        part[tid] += t;
        __syncthreads();
    }
    int run = part[tid] - s;  // exclusive prefix of this thread's segment
    for (int i = begin; i < end && i < N; ++i) {
        offs[i] = run; cursor[i] = run; run += cnt[i];
    }
    if (tid == 1023) offs[N] = part[1023];
}

__global__ void fill_kernel(const int* __restrict__ src, const int* __restrict__ dst,
                            int* __restrict__ cursor, int* __restrict__ csr_src, int E) {
    for (int e = blockIdx.x * blockDim.x + threadIdx.x; e < E; e += gridDim.x * blockDim.x) {
        int p = atomicAdd(&cursor[dst[e]], 1);
        csr_src[p] = src[e];
    }
}

// ---------------- per-dst edge softmax + aggregation + W_out ----------------
__global__ __launch_bounds__(64) void agg_kernel(
    const float* __restrict__ h_root, const float* __restrict__ el,
    const float* __restrict__ er, const int* __restrict__ offs,
    const int* __restrict__ csr_src, const float* __restrict__ W_out,
    const float* __restrict__ bias_g, float* __restrict__ rst)
{
    const int n = blockIdx.x;
    const int lane = threadIdx.x;
    const int beg = offs[n];
    const int deg = offs[n + 1] - beg;
    __shared__ int s_src[64];
    __shared__ float s_ez[64][NHEADS];
    __shared__ float s_agg[NHEADS][HD];

    float er4[NHEADS];
    #pragma unroll
    for (int h = 0; h < NHEADS; ++h) er4[h] = er[(size_t)n * NHEADS + h];

    // pass 1: per-head max over in-edges
    float mx[NHEADS] = {-INFINITY, -INFINITY, -INFINITY, -INFINITY};
    for (int j = lane; j < deg; j += 64) {
        const int src = csr_src[beg + j];
        #pragma unroll
        for (int h = 0; h < NHEADS; ++h) {
            float v = el[(size_t)src * NHEADS + h] + er4[h];
            v = v > 0.f ? v : 0.2f * v;
            mx[h] = fmaxf(mx[h], v);
        }
    }
    #pragma unroll
    for (int h = 0; h < NHEADS; ++h)
        for (int off = 1; off < 64; off <<= 1)
            mx[h] = fmaxf(mx[h], __shfl_xor(mx[h], off));

    // pass 2: exp, sum, and weighted accumulation of h_root[src] (channel = lane)
    float acc[NHEADS] = {0.f, 0.f, 0.f, 0.f};
    float ps[NHEADS] = {0.f, 0.f, 0.f, 0.f};
    for (int j0 = 0; j0 < deg; j0 += 64) {
        const int j = j0 + lane;
        float ezl[NHEADS] = {0.f, 0.f, 0.f, 0.f};
        int srcj = 0;
        if (j < deg) {
            srcj = csr_src[beg + j];
            #pragma unroll
            for (int h = 0; h < NHEADS; ++h) {
                float v = el[(size_t)srcj * NHEADS + h] + er4[h];
                v = v > 0.f ? v : 0.2f * v;
                float ez = expf(v - mx[h]);
                ezl[h] = ez; ps[h] += ez;
            }
        }
        s_src[lane] = srcj;
        #pragma unroll
        for (int h = 0; h < NHEADS; ++h) s_ez[lane][h] = ezl[h];
        __syncthreads();
        const int cnt = min(64, deg - j0);
        #pragma unroll 8
        for (int jj = 0; jj < cnt; ++jj) {
            const float hv = h_root[(size_t)s_src[jj] * HD + lane];
            #pragma unroll
            for (int h = 0; h < NHEADS; ++h) acc[h] = fmaf(s_ez[jj][h], hv, acc[h]);
        }
        __syncthreads();
    }
    #pragma unroll
    for (int h = 0; h < NHEADS; ++h)
        for (int off = 1; off < 64; off <<= 1)
            ps[h] += __shfl_xor(ps[h], off);

    #pragma unroll
    for (int h = 0; h < NHEADS; ++h) {
        float inv = (deg > 0) ? 1.f / ps[h] : 0.f;
        s_agg[h][lane] = acc[h] * inv;
    }
    __syncthreads();

    // rst[n,h,o] = sum_c agg[h][c]*W_out[o][c] + bias_g[h*32+o]
    #pragma unroll
    for (int idx = lane; idx < NHEADS * OUTD; idx += 64) {
        const int h = idx >> 5, o = idx & 31;
        float s = bias_g[idx];
        #pragma unroll 4
        for (int c = 0; c < HD; ++c) s = fmaf(s_agg[h][c], W_out[o * HD + c], s);
        rst[(size_t)n * 128 + idx] = s;
    }
}

// ---------------- axis-0 softmax stats: one block per column ----------------
__global__ __launch_bounds__(256) void colstat_kernel(
    const float* __restrict__ rst, float* __restrict__ colmax,
    float* __restrict__ colsum, int N)
{
    const int c = blockIdx.x;  // 0..127
    const int tid = threadIdx.x;
    __shared__ float red[256];
    float mx = -INFINITY;
    for (int n = tid; n < N; n += 256) mx = fmaxf(mx, rst[(size_t)n * 128 + c]);
    red[tid] = mx;
    __syncthreads();
    for (int s = 128; s > 0; s >>= 1) {
        if (tid < s) red[tid] = fmaxf(red[tid], red[tid + s]);
        __syncthreads();
    }
    const float m = red[0];
    __syncthreads();
    float sm = 0.f;
    for (int n = tid; n < N; n += 256) sm += expf(rst[(size_t)n * 128 + c] - m);
    red[tid] = sm;
    __syncthreads();
    for (int s = 128; s > 0; s >>= 1) {
        if (tid < s) red[tid] += red[tid + s];
        __syncthreads();
    }
    if (tid == 0) { colmax[c] = m; colsum[c] = red[0]; }
}

// ---------------- softmax + folded classifier ----------------
__global__ __launch_bounds__(256) void final_kernel(
    const float* __restrict__ rst, const float* __restrict__ colmax,
    const float* __restrict__ colsum, const float* __restrict__ W1,
    const float* __restrict__ b1, const float* __restrict__ W2,
    const float* __restrict__ b2, float* __restrict__ out, int N)
{
    __shared__ float M[2][OUTD];
    __shared__ float bv[2];
    __shared__ float cm[128], cs[128];
    const int tid = threadIdx.x;
    if (tid < 64) {
        const int r = tid >> 5, o = tid & 31;
        float s = 0.f;
        #pragma unroll
        for (int k = 0; k < 16; ++k) s = fmaf(W2[r * 16 + k], W1[k * 32 + o], s);
        M[r][o] = s;
    }
    if (tid < 2) {
        float s = b2[tid];
        #pragma unroll
        for (int k = 0; k < 16; ++k) s = fmaf(b1[k], W2[tid * 16 + k], s);
        bv[tid] = s;
    }
    if (tid < 128) { cm[tid] = colmax[tid]; cs[tid] = colsum[tid]; }
    __syncthreads();
    for (int row = blockIdx.x * 256 + tid; row < N * 4; row += gridDim.x * 256) {
        const int n = row >> 2, h = row & 3;
        const float* r = rst + (size_t)n * 128 + h * 32;
        float a0 = bv[0], a1 = bv[1];
        #pragma unroll 4
        for (int o = 0; o < OUTD; ++o) {
            const int c = h * 32 + o;
            float p = expf(r[o] - cm[c]) / cs[c];
            a0 = fmaf(p, M[0][o], a0);
            a1 = fmaf(p, M[1][o], a1);
        }
        out[(size_t)row * 2 + 0] = a0;
        out[(size_t)row * 2 + 1] = a1;
    }
}

extern "C" void kernel_launch(void* const* d_in, const int* in_sizes, int n_in,
                              void* d_out, int out_size, void* d_ws, size_t ws_size,
                              hipStream_t stream) {
    const float* ast_x   = (const float*)d_in[0];
    const float* c_init  = (const float*)d_in[1];
    const float* cfg_type= (const float*)d_in[2];
    const float* W_iou   = (const float*)d_in[3];
    const float* b_iou   = (const float*)d_in[4];
    const float* U_iou   = (const float*)d_in[5];
    const float* U_f_W   = (const float*)d_in[6];
    const float* U_f_b   = (const float*)d_in[7];
    const float* Wt      = (const float*)d_in[8];
    const float* Wfc     = (const float*)d_in[9];
    const float* attn_l  = (const float*)d_in[10];
    const float* attn_r  = (const float*)d_in[11];
    const float* W_out   = (const float*)d_in[12];
    const float* bias_g  = (const float*)d_in[13];
    const float* W1      = (const float*)d_in[14];
    const float* b1      = (const float*)d_in[15];
    const float* W2      = (const float*)d_in[16];
    const float* b2      = (const float*)d_in[17];
    const int* edge_src  = (const int*)d_in[18];
    const int* edge_dst  = (const int*)d_in[19];

    const int N = in_sizes[2] / XD;      // 20000
    const int E = in_sizes[18];          // 640000
    (void)n_in; (void)out_size; (void)ws_size;

    char* w = (char*)d_ws;
    auto take = [&](size_t bytes) { char* p = w; w += (bytes + 255) & ~(size_t)255; return p; };
    float* h_root  = (float*)take((size_t)N * HD * 4);
    float* el      = (float*)take((size_t)N * NHEADS * 4);
    float* er      = (float*)take((size_t)N * NHEADS * 4);
    int*   cnt     = (int*)take((size_t)N * 4);
    int*   offs    = (int*)take(((size_t)N + 1) * 4);
    int*   cursor  = (int*)take((size_t)N * 4);
    int*   csr_src = (int*)take((size_t)E * 4);
    float* rst     = (float*)take((size_t)N * 128 * 4);
    float* colmax  = (float*)take(128 * 4);
    float* colsum  = (float*)take(128 * 4);

    zero_int<<<(N + 255) / 256, 256, 0, stream>>>(cnt, N);
    treelstm_kernel<<<N, 256, 0, stream>>>(ast_x, c_init, W_iou, b_iou, U_iou, U_f_W, U_f_b, h_root);
    featatt_kernel<<<N, 128, 0, stream>>>(cfg_type, Wt, Wfc, attn_l, attn_r, el, er);
    count_kernel<<<1024, 256, 0, stream>>>(edge_dst, cnt, E);
    scan_kernel<<<1, 1024, 0, stream>>>(cnt, offs, cursor, N);
    fill_kernel<<<1024, 256, 0, stream>>>(edge_src, edge_dst, cursor, csr_src, E);
    agg_kernel<<<N, 64, 0, stream>>>(h_root, el, er, offs, csr_src, W_out, bias_g, rst);
    colstat_kernel<<<128, 256, 0, stream>>>(rst, colmax, colsum, N);
    final_kernel<<<(N * 4 + 255) / 256, 256, 0, stream>>>(rst, colmax, colsum, W1, b1, W2, b2, (float*)d_out, N);
}

// Round 2
// 459.227 us; speedup vs baseline: 8.5385x; 8.5385x over previous
//
#include <hip/hip_runtime.h>
#include <hip/hip_bf16.h>
#include <math.h>

#define XD 100
#define HD 64
#define GD 192
#define TL 15
#define NHEADS 4
#define OUTD 32

typedef unsigned short ushort_t;
typedef __attribute__((ext_vector_type(8))) short bf16x8;
typedef __attribute__((ext_vector_type(4))) float f32x4;

__device__ __forceinline__ float sigmoidf_(float x) { return 1.0f / (1.0f + expf(-x)); }
__device__ __forceinline__ ushort_t f2bf(float x) {
    __hip_bfloat16 h = __float2bfloat16(x);
    return *reinterpret_cast<ushort_t*>(&h);
}
__device__ __forceinline__ float bf2f(ushort_t u) {
    unsigned int v = ((unsigned int)u) << 16;
    return __uint_as_float(v);
}

// ---------------- prep: pack W_iou / U_f_W into MFMA B-fragment layout, transpose U_iou ----------------
// B-frag for mfma_f32_16x16x32_bf16: lane l holds B[k = kblk*8+j][n0 + (l&15)], kblk = l>>4, j=0..7
__global__ __launch_bounds__(256) void prep_kernel(
    const float* __restrict__ W_iou, const float* __restrict__ U_f_W,
    const float* __restrict__ U_iou,
    ushort_t* __restrict__ Wb_iou, ushort_t* __restrict__ Wb_f,
    float* __restrict__ U_iou_T)
{
    int idx = blockIdx.x * 256 + threadIdx.x;
    if (idx < 24576) {                       // W_iou: 4 ktiles x 12 ntiles x 64 lanes x 8
        int j = idx & 7, l = (idx >> 3) & 63, f = idx >> 9;
        int kt = f / 12, nt = f % 12;
        int k = kt * 32 + ((l >> 4) * 8) + j;
        int nn = nt * 16 + (l & 15);
        float v = (k < XD) ? W_iou[nn * XD + k] : 0.f;
        Wb_iou[idx] = f2bf(v);
    } else if (idx < 24576 + 4096) {         // U_f_W: 2 ktiles x 4 ntiles x 64 x 8
        int t = idx - 24576;
        int j = t & 7, l = (t >> 3) & 63, f = t >> 9;
        int kt = f >> 2, nt = f & 3;
        int k = kt * 32 + ((l >> 4) * 8) + j;
        int nn = nt * 16 + (l & 15);
        Wb_f[t] = f2bf(U_f_W[nn * HD + k]);
    } else if (idx < 24576 + 4096 + 12288) { // U_iou_T[k][g]
        int t = idx - 24576 - 4096;
        int k = t / GD, g = t - k * GD;
        U_iou_T[t] = U_iou[g * HD + k];
    }
}

// ---------------- prep: fold attn into projection: B_lr[q][x], q=0..3 -> el, 4..7 -> er ----------------
__global__ __launch_bounds__(256) void prepB_kernel(
    const float* __restrict__ Wt, const float* __restrict__ Wfc,
    const float* __restrict__ attn_l, const float* __restrict__ attn_r,
    float* __restrict__ B_lr)
{
    __shared__ float A_s[8][HD];
    const int tid = threadIdx.x;
    for (int o = tid; o < 8 * HD; o += 256) {
        int q = o >> 6, c = o & 63;
        int h = q & 3;
        const float* attn = (q < 4) ? attn_l : attn_r;
        float s = 0.f;
        #pragma unroll 4
        for (int oo = 0; oo < OUTD; ++oo)
            s = fmaf(attn[h * OUTD + oo], Wfc[(h * OUTD + oo) * HD + c], s);
        A_s[q][c] = s;
    }
    __syncthreads();
    for (int o = tid; o < 8 * XD; o += 256) {
        int q = o / XD, x = o - q * XD;
        float s = 0.f;
        #pragma unroll 4
        for (int c = 0; c < HD; ++c)
            s = fmaf(A_s[q][c], Wt[c * XD + x], s);
        B_lr[o] = s;
    }
}

// ---------------- TreeLSTM with MFMA: one CFG node per block, 4 waves ----------------
__global__ __launch_bounds__(256) void treelstm_mfma(
    const float* __restrict__ ast_x, const float* __restrict__ c_init,
    const ushort_t* __restrict__ Wb_iou, const ushort_t* __restrict__ Wb_f,
    const float* __restrict__ b_iou, const float* __restrict__ U_iou_T,
    const float* __restrict__ U_f_b, float* __restrict__ h_root)
{
    __shared__ __align__(16) ushort_t xsb[16][136];   // bf16 X, K padded to 128, row-pad 8
    __shared__ float iou_s[16][200];                  // leaf iou (pad stride 200 vs 192)
    __shared__ __align__(16) ushort_t hlb[16][72];    // bf16 h_leaf, row-pad
    __shared__ float c_leaf[TL][HD];
    __shared__ float h_tild_s[HD];
    __shared__ float c_red_s[HD];
    __shared__ float iour[GD];

    const int n = blockIdx.x;
    const int tid = threadIdx.x;
    const int lane = tid & 63;
    const int w = tid >> 6;
    const int arow = lane & 15;
    const int kgrp = lane >> 4;

    // stage leaves (rows n*16+1 .. +15) as bf16, zero-pad k>=100 and row 15
    const float* xb = ast_x + ((size_t)n * 16 + 1) * XD;
    for (int i = tid; i < 16 * 128; i += 256) {
        int r = i >> 7, k = i & 127;
        float v = (r < TL && k < XD) ? xb[r * XD + k] : 0.f;
        xsb[r][k] = f2bf(v);
    }
    __syncthreads();

    // leaf GEMM: D[16,192] = X[16,128] @ W^T ; wave w handles ntiles {w, w+4, w+8}
    f32x4 acc[3] = {{0,0,0,0},{0,0,0,0},{0,0,0,0}};
    #pragma unroll
    for (int kt = 0; kt < 4; ++kt) {
        bf16x8 a = *(const bf16x8*)&xsb[arow][kt * 32 + kgrp * 8];
        #pragma unroll
        for (int j = 0; j < 3; ++j) {
            int nt = w + 4 * j;
            bf16x8 b = *(const bf16x8*)(Wb_iou + (((size_t)kt * 12 + nt) * 64 + lane) * 8);
            acc[j] = __builtin_amdgcn_mfma_f32_16x16x32_bf16(a, b, acc[j], 0, 0, 0);
        }
    }
    #pragma unroll
    for (int j = 0; j < 3; ++j) {
        int n0 = (w + 4 * j) * 16;
        #pragma unroll
        for (int r = 0; r < 4; ++r)
            iou_s[kgrp * 4 + r][n0 + arow] = acc[j][r];   // D: col=lane&15, row=(lane>>4)*4+r
    }
    __syncthreads();

    // leaf elementwise: c = sig(i)*tanh(u) + c0 ; h = sig(o)*tanh(c)
    const float* cb = c_init + ((size_t)n * 16 + 1) * HD;
    for (int idx = tid; idx < 16 * 64; idx += 256) {
        int t = idx >> 6, h = idx & 63;
        if (t < TL) {
            float iv = iou_s[t][h]       + b_iou[h];
            float ov = iou_s[t][64 + h]  + b_iou[64 + h];
            float uv = iou_s[t][128 + h] + b_iou[128 + h];
            float c = sigmoidf_(iv) * tanhf(uv) + cb[idx];
            c_leaf[t][h] = c;
            hlb[t][h] = f2bf(sigmoidf_(ov) * tanhf(c));
        } else {
            hlb[15][h] = 0;
        }
    }
    __syncthreads();

    // forget-gate GEMM: F[16,64] = h_leaf[16,64] @ U_f^T ; wave w -> ntile w
    f32x4 facc = {0, 0, 0, 0};
    #pragma unroll
    for (int kt = 0; kt < 2; ++kt) {
        bf16x8 a = *(const bf16x8*)&hlb[arow][kt * 32 + kgrp * 8];
        bf16x8 b = *(const bf16x8*)(Wb_f + (((size_t)kt * 4 + w) * 64 + lane) * 8);
        facc = __builtin_amdgcn_mfma_f32_16x16x32_bf16(a, b, facc, 0, 0, 0);
    }
    {
        const int h = w * 16 + arow;
        const float fb = U_f_b[h];
        float s = 0.f;
        #pragma unroll
        for (int r = 0; r < 4; ++r) {
            int row = kgrp * 4 + r;
            if (row < TL) s += sigmoidf_(facc[r] + fb) * c_leaf[row][h];
        }
        s += __shfl_xor(s, 16);
        s += __shfl_xor(s, 32);
        if (lane < 16) c_red_s[h] = s;
    }
    // h_tild
    if (tid < HD) {
        float hs = 0.f;
        #pragma unroll
        for (int t = 0; t < TL; ++t) hs += bf2f(hlb[t][tid]);
        h_tild_s[tid] = hs;
    }
    __syncthreads();

    // root iou: 192 dots of 64, coalesced via U_iou_T
    if (tid < GD) {
        float a2 = b_iou[tid];
        #pragma unroll 4
        for (int k = 0; k < HD; ++k)
            a2 = fmaf(h_tild_s[k], U_iou_T[k * GD + tid], a2);
        iour[tid] = a2;
    }
    __syncthreads();

    if (tid < HD) {
        float c = sigmoidf_(iour[tid]) * tanhf(iour[tid + 128]) + c_red_s[tid];
        h_root[(size_t)n * HD + tid] = sigmoidf_(iour[tid + 64]) * tanhf(c);
    }
}

// ---------------- el/er via folded projection ----------------
__global__ __launch_bounds__(256) void elr_kernel(
    const float* __restrict__ cfg_type, const float* __restrict__ B_lr,
    float* __restrict__ el, float* __restrict__ er, int N)
{
    __shared__ float xs[64 * XD];
    __shared__ float Bs[8 * XD];
    const int tid = threadIdx.x;
    const int base = blockIdx.x * 64;
    for (int i = tid; i < 8 * XD; i += 256) Bs[i] = B_lr[i];
    const size_t goff = (size_t)base * XD;
    long lim = (long)N * XD - (long)goff;
    if (lim > 64 * XD) lim = 64 * XD;
    for (int i = tid; i < lim; i += 256) xs[i] = cfg_type[goff + i];
    __syncthreads();
    for (int o = tid; o < 512; o += 256) {
        int r = o >> 3, q = o & 7;
        int node = base + r;
        if (node < N) {
            float s = 0.f;
            #pragma unroll 4
            for (int k = 0; k < XD; ++k)
                s = fmaf(xs[r * XD + k], Bs[q * XD + k], s);
            ((q < 4) ? el : er)[(size_t)node * NHEADS + (q & 3)] = s;
        }
    }
}

// ---------------- CSR build ----------------
__global__ void zero_int(int* __restrict__ p, int n) {
    int i = blockIdx.x * blockDim.x + threadIdx.x;
    if (i < n) p[i] = 0;
}

__global__ void count_kernel(const int* __restrict__ dst, int* __restrict__ cnt, int E) {
    for (int e = blockIdx.x * blockDim.x + threadIdx.x; e < E; e += gridDim.x * blockDim.x)
        atomicAdd(&cnt[dst[e]], 1);
}

__global__ __launch_bounds__(1024) void scan_kernel(
    const int* __restrict__ cnt, int* __restrict__ offs, int* __restrict__ cursor, int N)
{
    __shared__ int part[1024];
    const int tid = threadIdx.x;
    const int per = (N + 1023) >> 10;
    int begin = tid * per;
    int end = begin + per; if (end > N) end = N;
    int s = 0;
    for (int i = begin; i < end && i < N; ++i) s += cnt[i];
    part[tid] = s;
    __syncthreads();
    for (int off = 1; off < 1024; off <<= 1) {
        int t = (tid >= off) ? part[tid - off] : 0;
        __syncthreads();
        part[tid] += t;
        __syncthreads();
    }
    int run = part[tid] - s;
    for (int i = begin; i < end && i < N; ++i) {
        offs[i] = run; cursor[i] = run; run += cnt[i];
    }
    if (tid == 1023) offs[N] = part[1023];
}

__global__ void fill_kernel(const int* __restrict__ src, const int* __restrict__ dst,
                            int* __restrict__ cursor, int* __restrict__ csr_src, int E) {
    for (int e = blockIdx.x * blockDim.x + threadIdx.x; e < E; e += gridDim.x * blockDim.x) {
        int p = atomicAdd(&cursor[dst[e]], 1);
        csr_src[p] = src[e];
    }
}

// ---------------- per-dst edge softmax + aggregation + W_out ----------------
__global__ __launch_bounds__(64) void agg_kernel(
    const float* __restrict__ h_root, const float* __restrict__ el,
    const float* __restrict__ er, const int* __restrict__ offs,
    const int* __restrict__ csr_src, const float* __restrict__ W_out,
    const float* __restrict__ bias_g, float* __restrict__ rst)
{
    const int n = blockIdx.x;
    const int lane = threadIdx.x;
    const int beg = offs[n];
    const int deg = offs[n + 1] - beg;
    __shared__ int s_src[64];
    __shared__ float s_ez[64][NHEADS];
    __shared__ float s_agg[NHEADS][HD];

    float er4[NHEADS];
    #pragma unroll
    for (int h = 0; h < NHEADS; ++h) er4[h] = er[(size_t)n * NHEADS + h];

    float mx[NHEADS] = {-INFINITY, -INFINITY, -INFINITY, -INFINITY};
    for (int j = lane; j < deg; j += 64) {
        const int src = csr_src[beg + j];
        #pragma unroll
        for (int h = 0; h < NHEADS; ++h) {
            float v = el[(size_t)src * NHEADS + h] + er4[h];
            v = v > 0.f ? v : 0.2f * v;
            mx[h] = fmaxf(mx[h], v);
        }
    }
    #pragma unroll
    for (int h = 0; h < NHEADS; ++h)
        for (int off = 1; off < 64; off <<= 1)
            mx[h] = fmaxf(mx[h], __shfl_xor(mx[h], off));

    float acc[NHEADS] = {0.f, 0.f, 0.f, 0.f};
    float ps[NHEADS] = {0.f, 0.f, 0.f, 0.f};
    for (int j0 = 0; j0 < deg; j0 += 64) {
        const int j = j0 + lane;
        float ezl[NHEADS] = {0.f, 0.f, 0.f, 0.f};
        int srcj = 0;
        if (j < deg) {
            srcj = csr_src[beg + j];
            #pragma unroll
            for (int h = 0; h < NHEADS; ++h) {
                float v = el[(size_t)srcj * NHEADS + h] + er4[h];
                v = v > 0.f ? v : 0.2f * v;
                float ez = expf(v - mx[h]);
                ezl[h] = ez; ps[h] += ez;
            }
        }
        s_src[lane] = srcj;
        #pragma unroll
        for (int h = 0; h < NHEADS; ++h) s_ez[lane][h] = ezl[h];
        __syncthreads();
        const int cnt = min(64, deg - j0);
        #pragma unroll 8
        for (int jj = 0; jj < cnt; ++jj) {
            const float hv = h_root[(size_t)s_src[jj] * HD + lane];
            #pragma unroll
            for (int h = 0; h < NHEADS; ++h) acc[h] = fmaf(s_ez[jj][h], hv, acc[h]);
        }
        __syncthreads();
    }
    #pragma unroll
    for (int h = 0; h < NHEADS; ++h)
        for (int off = 1; off < 64; off <<= 1)
            ps[h] += __shfl_xor(ps[h], off);

    #pragma unroll
    for (int h = 0; h < NHEADS; ++h) {
        float inv = (deg > 0) ? 1.f / ps[h] : 0.f;
        s_agg[h][lane] = acc[h] * inv;
    }
    __syncthreads();

    #pragma unroll
    for (int idx = lane; idx < NHEADS * OUTD; idx += 64) {
        const int h = idx >> 5, o = idx & 31;
        float s = bias_g[idx];
        #pragma unroll 4
        for (int c = 0; c < HD; ++c) s = fmaf(s_agg[h][c], W_out[o * HD + c], s);
        rst[(size_t)n * 128 + idx] = s;
    }
}

// ---------------- axis-0 softmax stats ----------------
__global__ __launch_bounds__(256) void colstat_kernel(
    const float* __restrict__ rst, float* __restrict__ colmax,
    float* __restrict__ colsum, int N)
{
    const int c = blockIdx.x;
    const int tid = threadIdx.x;
    __shared__ float red[256];
    float mx = -INFINITY;
    for (int n = tid; n < N; n += 256) mx = fmaxf(mx, rst[(size_t)n * 128 + c]);
    red[tid] = mx;
    __syncthreads();
    for (int s = 128; s > 0; s >>= 1) {
        if (tid < s) red[tid] = fmaxf(red[tid], red[tid + s]);
        __syncthreads();
    }
    const float m = red[0];
    __syncthreads();
    float sm = 0.f;
    for (int n = tid; n < N; n += 256) sm += expf(rst[(size_t)n * 128 + c] - m);
    red[tid] = sm;
    __syncthreads();
    for (int s = 128; s > 0; s >>= 1) {
        if (tid < s) red[tid] += red[tid + s];
        __syncthreads();
    }
    if (tid == 0) { colmax[c] = m; colsum[c] = red[0]; }
}

// ---------------- softmax + folded classifier ----------------
__global__ __launch_bounds__(256) void final_kernel(
    const float* __restrict__ rst, const float* __restrict__ colmax,
    const float* __restrict__ colsum, const float* __restrict__ W1,
    const float* __restrict__ b1, const float* __restrict__ W2,
    const float* __restrict__ b2, float* __restrict__ out, int N)
{
    __shared__ float M[2][OUTD];
    __shared__ float bv[2];
    __shared__ float cm[128], cs[128];
    const int tid = threadIdx.x;
    if (tid < 64) {
        const int r = tid >> 5, o = tid & 31;
        float s = 0.f;
        #pragma unroll
        for (int k = 0; k < 16; ++k) s = fmaf(W2[r * 16 + k], W1[k * 32 + o], s);
        M[r][o] = s;
    }
    if (tid < 2) {
        float s = b2[tid];
        #pragma unroll
        for (int k = 0; k < 16; ++k) s = fmaf(b1[k], W2[tid * 16 + k], s);
        bv[tid] = s;
    }
    if (tid < 128) { cm[tid] = colmax[tid]; cs[tid] = colsum[tid]; }
    __syncthreads();
    for (int row = blockIdx.x * 256 + tid; row < N * 4; row += gridDim.x * 256) {
        const int n = row >> 2, h = row & 3;
        const float* r = rst + (size_t)n * 128 + h * 32;
        float a0 = bv[0], a1 = bv[1];
        #pragma unroll 4
        for (int o = 0; o < OUTD; ++o) {
            const int c = h * 32 + o;
            float p = expf(r[o] - cm[c]) / cs[c];
            a0 = fmaf(p, M[0][o], a0);
            a1 = fmaf(p, M[1][o], a1);
        }
        out[(size_t)row * 2 + 0] = a0;
        out[(size_t)row * 2 + 1] = a1;
    }
}

extern "C" void kernel_launch(void* const* d_in, const int* in_sizes, int n_in,
                              void* d_out, int out_size, void* d_ws, size_t ws_size,
                              hipStream_t stream) {
    const float* ast_x   = (const float*)d_in[0];
    const float* c_init  = (const float*)d_in[1];
    const float* cfg_type= (const float*)d_in[2];
    const float* W_iou   = (const float*)d_in[3];
    const float* b_iou   = (const float*)d_in[4];
    const float* U_iou   = (const float*)d_in[5];
    const float* U_f_W   = (const float*)d_in[6];
    const float* U_f_b   = (const float*)d_in[7];
    const float* Wt      = (const float*)d_in[8];
    const float* Wfc     = (const float*)d_in[9];
    const float* attn_l  = (const float*)d_in[10];
    const float* attn_r  = (const float*)d_in[11];
    const float* W_out   = (const float*)d_in[12];
    const float* bias_g  = (const float*)d_in[13];
    const float* W1      = (const float*)d_in[14];
    const float* b1      = (const float*)d_in[15];
    const float* W2      = (const float*)d_in[16];
    const float* b2      = (const float*)d_in[17];
    const int* edge_src  = (const int*)d_in[18];
    const int* edge_dst  = (const int*)d_in[19];

    const int N = in_sizes[2] / XD;      // 20000
    const int E = in_sizes[18];          // 640000
    (void)n_in; (void)out_size; (void)ws_size;

    char* w = (char*)d_ws;
    auto take = [&](size_t bytes) { char* p = w; w += (bytes + 255) & ~(size_t)255; return p; };
    float*    h_root  = (float*)take((size_t)N * HD * 4);
    float*    el      = (float*)take((size_t)N * NHEADS * 4);
    float*    er      = (float*)take((size_t)N * NHEADS * 4);
    int*      cnt     = (int*)take((size_t)N * 4);
    int*      offs    = (int*)take(((size_t)N + 1) * 4);
    int*      cursor  = (int*)take((size_t)N * 4);
    int*      csr_src = (int*)take((size_t)E * 4);
    float*    rst     = (float*)take((size_t)N * 128 * 4);
    float*    colmax  = (float*)take(128 * 4);
    float*    colsum  = (float*)take(128 * 4);
    ushort_t* Wb_iou  = (ushort_t*)take(24576 * 2);
    ushort_t* Wb_f    = (ushort_t*)take(4096 * 2);
    float*    U_iou_T = (float*)take(12288 * 4);
    float*    B_lr    = (float*)take(800 * 4);

    prep_kernel<<<160, 256, 0, stream>>>(W_iou, U_f_W, U_iou, Wb_iou, Wb_f, U_iou_T);
    prepB_kernel<<<1, 256, 0, stream>>>(Wt, Wfc, attn_l, attn_r, B_lr);
    zero_int<<<(N + 255) / 256, 256, 0, stream>>>(cnt, N);
    count_kernel<<<1024, 256, 0, stream>>>(edge_dst, cnt, E);
    scan_kernel<<<1, 1024, 0, stream>>>(cnt, offs, cursor, N);
    fill_kernel<<<1024, 256, 0, stream>>>(edge_src, edge_dst, cursor, csr_src, E);
    treelstm_mfma<<<N, 256, 0, stream>>>(ast_x, c_init, Wb_iou, Wb_f, b_iou, U_iou_T, U_f_b, h_root);
    elr_kernel<<<(N + 63) / 64, 256, 0, stream>>>(cfg_type, B_lr, el, er, N);
    agg_kernel<<<N, 64, 0, stream>>>(h_root, el, er, offs, csr_src, W_out, bias_g, rst);
    colstat_kernel<<<128, 256, 0, stream>>>(rst, colmax, colsum, N);
    final_kernel<<<(N * 4 + 255) / 256, 256, 0, stream>>>(rst, colmax, colsum, W1, b1, W2, b2, (float*)d_out, N);
}

// Round 3
// 364.751 us; speedup vs baseline: 10.7501x; 1.2590x over previous
//
#include <hip/hip_runtime.h>
#include <hip/hip_bf16.h>
#include <math.h>

#define XD 100
#define HD 64
#define GD 192
#define TL 15
#define NHEADS 4
#define OUTD 32
#define TPB_TREES 10

typedef unsigned short ushort_t;
typedef __attribute__((ext_vector_type(8))) short bf16x8;
typedef __attribute__((ext_vector_type(4))) float f32x4;

__device__ __forceinline__ ushort_t f2bf(float x) {
    __hip_bfloat16 h = __float2bfloat16(x);
    return *reinterpret_cast<ushort_t*>(&h);
}
__device__ __forceinline__ float fsig(float x) {
    return __builtin_amdgcn_rcpf(1.0f + __expf(-x));
}
__device__ __forceinline__ float ftanh(float x) {
    float e = __expf(-2.0f * fabsf(x));
    float t = 1.0f - 2.0f * e * __builtin_amdgcn_rcpf(1.0f + e);
    return copysignf(t, x);
}
__device__ __forceinline__ bf16x8 pack8(float4 lo, float4 hi) {
    bf16x8 a;
    a[0] = (short)f2bf(lo.x); a[1] = (short)f2bf(lo.y);
    a[2] = (short)f2bf(lo.z); a[3] = (short)f2bf(lo.w);
    a[4] = (short)f2bf(hi.x); a[5] = (short)f2bf(hi.y);
    a[6] = (short)f2bf(hi.z); a[7] = (short)f2bf(hi.w);
    return a;
}

// ---------------- prep: pack W_iou / U_f_W / U_iou into MFMA B-fragment layout ----------------
// B-frag for mfma_f32_16x16x32_bf16: lane l holds B[k = (l>>4)*8+j][n0 + (l&15)], j=0..7
__global__ __launch_bounds__(256) void prep_kernel(
    const float* __restrict__ W_iou, const float* __restrict__ U_f_W,
    const float* __restrict__ U_iou,
    ushort_t* __restrict__ Wb_iou, ushort_t* __restrict__ Wb_f,
    ushort_t* __restrict__ Wb_u)
{
    int idx = blockIdx.x * 256 + threadIdx.x;
    if (idx < 24576) {                       // W_iou: 4 ktiles x 12 ntiles x 64 lanes x 8
        int j = idx & 7, l = (idx >> 3) & 63, f = idx >> 9;
        int kt = f / 12, nt = f % 12;
        int k = kt * 32 + ((l >> 4) * 8) + j;
        int nn = nt * 16 + (l & 15);
        float v = (k < XD) ? W_iou[nn * XD + k] : 0.f;
        Wb_iou[idx] = f2bf(v);
    } else if (idx < 24576 + 4096) {         // U_f_W: 2 ktiles x 4 ntiles
        int t = idx - 24576;
        int j = t & 7, l = (t >> 3) & 63, f = t >> 9;
        int kt = f >> 2, nt = f & 3;
        int k = kt * 32 + ((l >> 4) * 8) + j;
        int nn = nt * 16 + (l & 15);
        Wb_f[t] = f2bf(U_f_W[nn * HD + k]);
    } else if (idx < 24576 + 4096 + 12288) { // U_iou: 2 ktiles x 12 ntiles
        int t = idx - 24576 - 4096;
        int j = t & 7, l = (t >> 3) & 63, f = t >> 9;
        int kt = f / 12, nt = f % 12;
        int k = kt * 32 + ((l >> 4) * 8) + j;
        int g = nt * 16 + (l & 15);
        Wb_u[t] = f2bf(U_iou[g * HD + k]);
    }
}

// ---------------- prep: fold attn into projection: B_lr[q][x], q=0..3 -> el, 4..7 -> er ----------------
__global__ __launch_bounds__(256) void prepB_kernel(
    const float* __restrict__ Wt, const float* __restrict__ Wfc,
    const float* __restrict__ attn_l, const float* __restrict__ attn_r,
    float* __restrict__ B_lr)
{
    __shared__ float A_s[8][HD];
    const int tid = threadIdx.x;
    for (int o = tid; o < 8 * HD; o += 256) {
        int q = o >> 6, c = o & 63;
        int h = q & 3;
        const float* attn = (q < 4) ? attn_l : attn_r;
        float s = 0.f;
        #pragma unroll 4
        for (int oo = 0; oo < OUTD; ++oo)
            s = fmaf(attn[h * OUTD + oo], Wfc[(h * OUTD + oo) * HD + c], s);
        A_s[q][c] = s;
    }
    __syncthreads();
    for (int o = tid; o < 8 * XD; o += 256) {
        int q = o / XD, x = o - q * XD;
        float s = 0.f;
        #pragma unroll 4
        for (int c = 0; c < HD; ++c)
            s = fmaf(A_s[q][c], Wt[c * XD + x], s);
        B_lr[o] = s;
    }
}

// ---------------- TreeLSTM leaves+forget: 10 trees per block, in-register elementwise ----------------
__global__ __launch_bounds__(256) void treelstm_mfma(
    const float* __restrict__ ast_x, const float* __restrict__ c_init,
    const ushort_t* __restrict__ Wb_iou, const ushort_t* __restrict__ Wb_f,
    const float* __restrict__ b_iou, const float* __restrict__ U_f_b,
    float* __restrict__ h_tild_g, float* __restrict__ c_red_g, int Ntrees)
{
    __shared__ __align__(16) float xs[16][132];       // f32 X tile, K pad to 128(+4)
    __shared__ __align__(16) ushort_t hlb[16][72];    // bf16 h_leaf

    const int tid = threadIdx.x;
    const int lane = tid & 63;
    const int w = tid >> 6;
    const int arow = lane & 15;
    const int kgrp = lane >> 4;
    const int h = w * 16 + arow;

    // persistent B fragments (reused across trees)
    bf16x8 Bl[12];
    #pragma unroll
    for (int kt = 0; kt < 4; ++kt)
        #pragma unroll
        for (int j = 0; j < 3; ++j)
            Bl[kt * 3 + j] = *(const bf16x8*)(Wb_iou + (((size_t)kt * 12 + (w + 4 * j)) * 64 + lane) * 8);
    bf16x8 Bf[2];
    #pragma unroll
    for (int kt = 0; kt < 2; ++kt)
        Bf[kt] = *(const bf16x8*)(Wb_f + (((size_t)kt * 4 + w) * 64 + lane) * 8);

    const float bi = b_iou[h], bo = b_iou[64 + h], bu = b_iou[128 + h];
    const float fb = U_f_b[h];

    // zero pad region once (cols 100..131 all rows; row 15 cols 0..99)
    for (int i = tid; i < 16 * 32; i += 256) xs[i >> 5][100 + (i & 31)] = 0.f;
    for (int i = tid; i < 100; i += 256) xs[15][i] = 0.f;
    __syncthreads();

    for (int tt = 0; tt < TPB_TREES; ++tt) {
        const int n = blockIdx.x * TPB_TREES + tt;
        if (n >= Ntrees) break;  // uniform across block

        // stage X rows 0..14, cols 0..99 (contiguous 375 float4)
        const float4* xb4 = (const float4*)(ast_x + ((size_t)n * 16 + 1) * XD);
        for (int i4 = tid; i4 < 375; i4 += 256) {
            int r = i4 / 25, c4 = i4 - r * 25;
            *(float4*)&xs[r][c4 * 4] = xb4[i4];
        }
        __syncthreads();   // B1: xs ready; prev-iter hlb reads complete

        // leaf GEMM: wave w owns ntiles {w, w+4, w+8} -> (i,o,u) for same h per lane
        f32x4 a0 = {0,0,0,0}, a1 = {0,0,0,0}, a2 = {0,0,0,0};
        #pragma unroll
        for (int kt = 0; kt < 4; ++kt) {
            float4 lo = *(const float4*)&xs[arow][kt * 32 + kgrp * 8];
            float4 hi = *(const float4*)&xs[arow][kt * 32 + kgrp * 8 + 4];
            bf16x8 a = pack8(lo, hi);
            a0 = __builtin_amdgcn_mfma_f32_16x16x32_bf16(a, Bl[kt * 3 + 0], a0, 0, 0, 0);
            a1 = __builtin_amdgcn_mfma_f32_16x16x32_bf16(a, Bl[kt * 3 + 1], a1, 0, 0, 0);
            a2 = __builtin_amdgcn_mfma_f32_16x16x32_bf16(a, Bl[kt * 3 + 2], a2, 0, 0, 0);
        }

        // leaf elementwise fully in registers; write bf16 h_leaf to LDS
        const float* cb = c_init + ((size_t)n * 16 + 1) * HD;
        float cl[4];
        float hsum = 0.f;
        #pragma unroll
        for (int r = 0; r < 4; ++r) {
            int t = kgrp * 4 + r;
            float hl = 0.f, c = 0.f;
            if (t < TL) {
                float i_ = a0[r] + bi, o_ = a1[r] + bo, u_ = a2[r] + bu;
                c = fsig(i_) * ftanh(u_) + cb[t * HD + h];
                hl = fsig(o_) * ftanh(c);
            }
            cl[r] = c;
            hsum += hl;
            hlb[t][h] = f2bf(hl);
        }
        __syncthreads();   // B2: hlb ready

        // forget GEMM: F fragment layout == c_leaf register layout
        f32x4 fa = {0,0,0,0};
        #pragma unroll
        for (int kt = 0; kt < 2; ++kt) {
            bf16x8 a = *(const bf16x8*)&hlb[arow][kt * 32 + kgrp * 8];
            fa = __builtin_amdgcn_mfma_f32_16x16x32_bf16(a, Bf[kt], fa, 0, 0, 0);
        }
        float credsum = 0.f;
        #pragma unroll
        for (int r = 0; r < 4; ++r) {
            int t = kgrp * 4 + r;
            if (t < TL) credsum += fsig(fa[r] + fb) * cl[r];
        }
        hsum += __shfl_xor(hsum, 16);    hsum += __shfl_xor(hsum, 32);
        credsum += __shfl_xor(credsum, 16); credsum += __shfl_xor(credsum, 32);
        if (kgrp == 0) {
            h_tild_g[(size_t)n * HD + h] = hsum;
            c_red_g[(size_t)n * HD + h] = credsum;
        }
        // next iteration's B1 protects xs and hlb
    }
}

// ---------------- root: batched MFMA GEMM [N,64]@[64,192] + elementwise ----------------
__global__ __launch_bounds__(256) void root_kernel(
    const float* __restrict__ h_tild_g, const float* __restrict__ c_red_g,
    const ushort_t* __restrict__ Wb_u, const float* __restrict__ b_iou,
    float* __restrict__ h_root, int Ntrees)
{
    __shared__ __align__(16) float hts[16][68];
    const int tid = threadIdx.x, lane = tid & 63, w = tid >> 6;
    const int arow = lane & 15, kgrp = lane >> 4;
    const int h = w * 16 + arow;
    const int m0 = blockIdx.x * 16;

    for (int i4 = tid; i4 < 16 * 16; i4 += 256) {
        int r = i4 >> 4, c4 = i4 & 15;
        *(float4*)&hts[r][c4 * 4] = *(const float4*)&h_tild_g[(size_t)(m0 + r) * HD + c4 * 4];
    }
    __syncthreads();

    f32x4 a0 = {0,0,0,0}, a1 = {0,0,0,0}, a2 = {0,0,0,0};
    #pragma unroll
    for (int kt = 0; kt < 2; ++kt) {
        float4 lo = *(const float4*)&hts[arow][kt * 32 + kgrp * 8];
        float4 hi = *(const float4*)&hts[arow][kt * 32 + kgrp * 8 + 4];
        bf16x8 a = pack8(lo, hi);
        bf16x8 b0 = *(const bf16x8*)(Wb_u + (((size_t)kt * 12 + w)     * 64 + lane) * 8);
        bf16x8 b1 = *(const bf16x8*)(Wb_u + (((size_t)kt * 12 + w + 4) * 64 + lane) * 8);
        bf16x8 b2 = *(const bf16x8*)(Wb_u + (((size_t)kt * 12 + w + 8) * 64 + lane) * 8);
        a0 = __builtin_amdgcn_mfma_f32_16x16x32_bf16(a, b0, a0, 0, 0, 0);
        a1 = __builtin_amdgcn_mfma_f32_16x16x32_bf16(a, b1, a1, 0, 0, 0);
        a2 = __builtin_amdgcn_mfma_f32_16x16x32_bf16(a, b2, a2, 0, 0, 0);
    }
    const float bi = b_iou[h], bo = b_iou[64 + h], bu = b_iou[128 + h];
    #pragma unroll
    for (int r = 0; r < 4; ++r) {
        int m = m0 + kgrp * 4 + r;
        if (m < Ntrees) {
            float c = fsig(a0[r] + bi) * ftanh(a2[r] + bu) + c_red_g[(size_t)m * HD + h];
            h_root[(size_t)m * HD + h] = fsig(a1[r] + bo) * ftanh(c);
        }
    }
}

// ---------------- el/er via folded projection ----------------
__global__ __launch_bounds__(256) void elr_kernel(
    const float* __restrict__ cfg_type, const float* __restrict__ B_lr,
    float* __restrict__ el, float* __restrict__ er, int N)
{
    __shared__ float xs[64 * XD];
    __shared__ float Bs[8 * XD];
    const int tid = threadIdx.x;
    const int base = blockIdx.x * 64;
    for (int i = tid; i < 8 * XD; i += 256) Bs[i] = B_lr[i];
    const size_t goff = (size_t)base * XD;
    long lim = (long)N * XD - (long)goff;
    if (lim > 64 * XD) lim = 64 * XD;
    for (int i = tid; i < lim; i += 256) xs[i] = cfg_type[goff + i];
    __syncthreads();
    for (int o = tid; o < 512; o += 256) {
        int r = o >> 3, q = o & 7;
        int node = base + r;
        if (node < N) {
            float s = 0.f;
            #pragma unroll 4
            for (int k = 0; k < XD; ++k)
                s = fmaf(xs[r * XD + k], Bs[q * XD + k], s);
            ((q < 4) ? el : er)[(size_t)node * NHEADS + (q & 3)] = s;
        }
    }
}

// ---------------- CSR build ----------------
__global__ void zero_int(int* __restrict__ p, int n) {
    int i = blockIdx.x * blockDim.x + threadIdx.x;
    if (i < n) p[i] = 0;
}

__global__ void count_kernel(const int* __restrict__ dst, int* __restrict__ cnt, int E) {
    for (int e = blockIdx.x * blockDim.x + threadIdx.x; e < E; e += gridDim.x * blockDim.x)
        atomicAdd(&cnt[dst[e]], 1);
}

__global__ __launch_bounds__(1024) void scan_kernel(
    const int* __restrict__ cnt, int* __restrict__ offs, int* __restrict__ cursor, int N)
{
    __shared__ int part[1024];
    const int tid = threadIdx.x;
    const int per = (N + 1023) >> 10;
    int begin = tid * per;
    int end = begin + per; if (end > N) end = N;
    int s = 0;
    for (int i = begin; i < end && i < N; ++i) s += cnt[i];
    part[tid] = s;
    __syncthreads();
    for (int off = 1; off < 1024; off <<= 1) {
        int t = (tid >= off) ? part[tid - off] : 0;
        __syncthreads();
        part[tid] += t;
        __syncthreads();
    }
    int run = part[tid] - s;
    for (int i = begin; i < end && i < N; ++i) {
        offs[i] = run; cursor[i] = run; run += cnt[i];
    }
    if (tid == 1023) offs[N] = part[1023];
}

__global__ void fill_kernel(const int* __restrict__ src, const int* __restrict__ dst,
                            int* __restrict__ cursor, int* __restrict__ csr_src, int E) {
    for (int e = blockIdx.x * blockDim.x + threadIdx.x; e < E; e += gridDim.x * blockDim.x) {
        int p = atomicAdd(&cursor[dst[e]], 1);
        csr_src[p] = src[e];
    }
}

// ---------------- per-dst edge softmax + aggregation + W_out ----------------
__global__ __launch_bounds__(64) void agg_kernel(
    const float* __restrict__ h_root, const float* __restrict__ el,
    const float* __restrict__ er, const int* __restrict__ offs,
    const int* __restrict__ csr_src, const float* __restrict__ W_out,
    const float* __restrict__ bias_g, float* __restrict__ rst)
{
    const int n = blockIdx.x;
    const int lane = threadIdx.x;
    const int beg = offs[n];
    const int deg = offs[n + 1] - beg;
    __shared__ int s_src[64];
    __shared__ float s_ez[64][NHEADS];
    __shared__ float s_agg[NHEADS][HD];

    float er4[NHEADS];
    #pragma unroll
    for (int hh = 0; hh < NHEADS; ++hh) er4[hh] = er[(size_t)n * NHEADS + hh];

    float acc[NHEADS] = {0.f, 0.f, 0.f, 0.f};
    float ps[NHEADS] = {0.f, 0.f, 0.f, 0.f};

    if (deg <= 64) {
        // fast path: one gather, everything in registers
        int srcj = 0;
        float v[NHEADS] = {-INFINITY, -INFINITY, -INFINITY, -INFINITY};
        if (lane < deg) {
            srcj = csr_src[beg + lane];
            #pragma unroll
            for (int hh = 0; hh < NHEADS; ++hh) {
                float x = el[(size_t)srcj * NHEADS + hh] + er4[hh];
                v[hh] = x > 0.f ? x : 0.2f * x;
            }
        }
        float mx[NHEADS];
        #pragma unroll
        for (int hh = 0; hh < NHEADS; ++hh) {
            mx[hh] = v[hh];
            for (int off = 1; off < 64; off <<= 1)
                mx[hh] = fmaxf(mx[hh], __shfl_xor(mx[hh], off));
        }
        float ez[NHEADS] = {0.f, 0.f, 0.f, 0.f};
        if (lane < deg) {
            #pragma unroll
            for (int hh = 0; hh < NHEADS; ++hh) { ez[hh] = __expf(v[hh] - mx[hh]); ps[hh] = ez[hh]; }
        }
        s_src[lane] = srcj;
        #pragma unroll
        for (int hh = 0; hh < NHEADS; ++hh) s_ez[lane][hh] = ez[hh];
        __syncthreads();
        for (int jj = 0; jj < deg; ++jj) {
            const float hv = h_root[(size_t)s_src[jj] * HD + lane];
            #pragma unroll
            for (int hh = 0; hh < NHEADS; ++hh) acc[hh] = fmaf(s_ez[jj][hh], hv, acc[hh]);
        }
    } else {
        // generic path
        float mx[NHEADS] = {-INFINITY, -INFINITY, -INFINITY, -INFINITY};
        for (int j = lane; j < deg; j += 64) {
            const int src = csr_src[beg + j];
            #pragma unroll
            for (int hh = 0; hh < NHEADS; ++hh) {
                float x = el[(size_t)src * NHEADS + hh] + er4[hh];
                x = x > 0.f ? x : 0.2f * x;
                mx[hh] = fmaxf(mx[hh], x);
            }
        }
        #pragma unroll
        for (int hh = 0; hh < NHEADS; ++hh)
            for (int off = 1; off < 64; off <<= 1)
                mx[hh] = fmaxf(mx[hh], __shfl_xor(mx[hh], off));
        for (int j0 = 0; j0 < deg; j0 += 64) {
            const int j = j0 + lane;
            float ezl[NHEADS] = {0.f, 0.f, 0.f, 0.f};
            int srcj = 0;
            if (j < deg) {
                srcj = csr_src[beg + j];
                #pragma unroll
                for (int hh = 0; hh < NHEADS; ++hh) {
                    float x = el[(size_t)srcj * NHEADS + hh] + er4[hh];
                    x = x > 0.f ? x : 0.2f * x;
                    float e = __expf(x - mx[hh]);
                    ezl[hh] = e; ps[hh] += e;
                }
            }
            s_src[lane] = srcj;
            #pragma unroll
            for (int hh = 0; hh < NHEADS; ++hh) s_ez[lane][hh] = ezl[hh];
            __syncthreads();
            const int cnt = min(64, deg - j0);
            #pragma unroll 8
            for (int jj = 0; jj < cnt; ++jj) {
                const float hv = h_root[(size_t)s_src[jj] * HD + lane];
                #pragma unroll
                for (int hh = 0; hh < NHEADS; ++hh) acc[hh] = fmaf(s_ez[jj][hh], hv, acc[hh]);
            }
            __syncthreads();
        }
    }

    #pragma unroll
    for (int hh = 0; hh < NHEADS; ++hh)
        for (int off = 1; off < 64; off <<= 1)
            ps[hh] += __shfl_xor(ps[hh], off);

    #pragma unroll
    for (int hh = 0; hh < NHEADS; ++hh) {
        float inv = (deg > 0) ? 1.f / ps[hh] : 0.f;
        s_agg[hh][lane] = acc[hh] * inv;
    }
    __syncthreads();

    #pragma unroll
    for (int idx = lane; idx < NHEADS * OUTD; idx += 64) {
        const int hh = idx >> 5, o = idx & 31;
        float s = bias_g[idx];
        #pragma unroll 4
        for (int c = 0; c < HD; ++c) s = fmaf(s_agg[hh][c], W_out[o * HD + c], s);
        rst[(size_t)n * 128 + idx] = s;
    }
}

// ---------------- axis-0 softmax stats ----------------
__global__ __launch_bounds__(256) void colstat_kernel(
    const float* __restrict__ rst, float* __restrict__ colmax,
    float* __restrict__ colsum, int N)
{
    const int c = blockIdx.x;
    const int tid = threadIdx.x;
    __shared__ float red[256];
    float mx = -INFINITY;
    for (int n = tid; n < N; n += 256) mx = fmaxf(mx, rst[(size_t)n * 128 + c]);
    red[tid] = mx;
    __syncthreads();
    for (int s = 128; s > 0; s >>= 1) {
        if (tid < s) red[tid] = fmaxf(red[tid], red[tid + s]);
        __syncthreads();
    }
    const float m = red[0];
    __syncthreads();
    float sm = 0.f;
    for (int n = tid; n < N; n += 256) sm += __expf(rst[(size_t)n * 128 + c] - m);
    red[tid] = sm;
    __syncthreads();
    for (int s = 128; s > 0; s >>= 1) {
        if (tid < s) red[tid] += red[tid + s];
        __syncthreads();
    }
    if (tid == 0) { colmax[c] = m; colsum[c] = red[0]; }
}

// ---------------- softmax + folded classifier ----------------
__global__ __launch_bounds__(256) void final_kernel(
    const float* __restrict__ rst, const float* __restrict__ colmax,
    const float* __restrict__ colsum, const float* __restrict__ W1,
    const float* __restrict__ b1, const float* __restrict__ W2,
    const float* __restrict__ b2, float* __restrict__ out, int N)
{
    __shared__ float M[2][OUTD];
    __shared__ float bv[2];
    __shared__ float cm[128], cs[128];
    const int tid = threadIdx.x;
    if (tid < 64) {
        const int r = tid >> 5, o = tid & 31;
        float s = 0.f;
        #pragma unroll
        for (int k = 0; k < 16; ++k) s = fmaf(W2[r * 16 + k], W1[k * 32 + o], s);
        M[r][o] = s;
    }
    if (tid < 2) {
        float s = b2[tid];
        #pragma unroll
        for (int k = 0; k < 16; ++k) s = fmaf(b1[k], W2[tid * 16 + k], s);
        bv[tid] = s;
    }
    if (tid < 128) { cm[tid] = colmax[tid]; cs[tid] = colsum[tid]; }
    __syncthreads();
    for (int row = blockIdx.x * 256 + tid; row < N * 4; row += gridDim.x * 256) {
        const int n = row >> 2, h = row & 3;
        const float* r = rst + (size_t)n * 128 + h * 32;
        float a0 = bv[0], a1 = bv[1];
        #pragma unroll 4
        for (int o = 0; o < OUTD; ++o) {
            const int c = h * 32 + o;
            float p = __expf(r[o] - cm[c]) / cs[c];
            a0 = fmaf(p, M[0][o], a0);
            a1 = fmaf(p, M[1][o], a1);
        }
        out[(size_t)row * 2 + 0] = a0;
        out[(size_t)row * 2 + 1] = a1;
    }
}

extern "C" void kernel_launch(void* const* d_in, const int* in_sizes, int n_in,
                              void* d_out, int out_size, void* d_ws, size_t ws_size,
                              hipStream_t stream) {
    const float* ast_x   = (const float*)d_in[0];
    const float* c_init  = (const float*)d_in[1];
    const float* cfg_type= (const float*)d_in[2];
    const float* W_iou   = (const float*)d_in[3];
    const float* b_iou   = (const float*)d_in[4];
    const float* U_iou   = (const float*)d_in[5];
    const float* U_f_W   = (const float*)d_in[6];
    const float* U_f_b   = (const float*)d_in[7];
    const float* Wt      = (const float*)d_in[8];
    const float* Wfc     = (const float*)d_in[9];
    const float* attn_l  = (const float*)d_in[10];
    const float* attn_r  = (const float*)d_in[11];
    const float* W_out   = (const float*)d_in[12];
    const float* bias_g  = (const float*)d_in[13];
    const float* W1      = (const float*)d_in[14];
    const float* b1      = (const float*)d_in[15];
    const float* W2      = (const float*)d_in[16];
    const float* b2      = (const float*)d_in[17];
    const int* edge_src  = (const int*)d_in[18];
    const int* edge_dst  = (const int*)d_in[19];

    const int N = in_sizes[2] / XD;      // 20000
    const int E = in_sizes[18];          // 640000
    (void)n_in; (void)out_size; (void)ws_size;

    char* w = (char*)d_ws;
    auto take = [&](size_t bytes) { char* p = w; w += (bytes + 255) & ~(size_t)255; return p; };
    float*    h_root  = (float*)take((size_t)N * HD * 4);
    float*    el      = (float*)take((size_t)N * NHEADS * 4);
    float*    er      = (float*)take((size_t)N * NHEADS * 4);
    int*      cnt     = (int*)take((size_t)N * 4);
    int*      offs    = (int*)take(((size_t)N + 1) * 4);
    int*      cursor  = (int*)take((size_t)N * 4);
    int*      csr_src = (int*)take((size_t)E * 4);
    float*    rst     = (float*)take((size_t)N * 128 * 4);
    float*    colmax  = (float*)take(128 * 4);
    float*    colsum  = (float*)take(128 * 4);
    ushort_t* Wb_iou  = (ushort_t*)take(24576 * 2);
    ushort_t* Wb_f    = (ushort_t*)take(4096 * 2);
    ushort_t* Wb_u    = (ushort_t*)take(12288 * 2);
    float*    B_lr    = (float*)take(800 * 4);
    // h_tild/c_red alias rst: produced by treelstm, consumed by root BEFORE agg writes rst
    float*    h_tild_g = rst;
    float*    c_red_g  = rst + (size_t)N * HD;

    prep_kernel<<<160, 256, 0, stream>>>(W_iou, U_f_W, U_iou, Wb_iou, Wb_f, Wb_u);
    prepB_kernel<<<1, 256, 0, stream>>>(Wt, Wfc, attn_l, attn_r, B_lr);
    zero_int<<<(N + 255) / 256, 256, 0, stream>>>(cnt, N);
    count_kernel<<<1024, 256, 0, stream>>>(edge_dst, cnt, E);
    scan_kernel<<<1, 1024, 0, stream>>>(cnt, offs, cursor, N);
    fill_kernel<<<1024, 256, 0, stream>>>(edge_src, edge_dst, cursor, csr_src, E);
    treelstm_mfma<<<(N + TPB_TREES - 1) / TPB_TREES, 256, 0, stream>>>(
        ast_x, c_init, Wb_iou, Wb_f, b_iou, U_f_b, h_tild_g, c_red_g, N);
    root_kernel<<<(N + 15) / 16, 256, 0, stream>>>(h_tild_g, c_red_g, Wb_u, b_iou, h_root, N);
    elr_kernel<<<(N + 63) / 64, 256, 0, stream>>>(cfg_type, B_lr, el, er, N);
    agg_kernel<<<N, 64, 0, stream>>>(h_root, el, er, offs, csr_src, W_out, bias_g, rst);
    colstat_kernel<<<128, 256, 0, stream>>>(rst, colmax, colsum, N);
    final_kernel<<<(N * 4 + 255) / 256, 256, 0, stream>>>(rst, colmax, colsum, W1, b1, W2, b2, (float*)d_out, N);
}

// Round 4
// 348.529 us; speedup vs baseline: 11.2504x; 1.0465x over previous
//
#include <hip/hip_runtime.h>
#include <hip/hip_bf16.h>
#include <math.h>

#define XD 100
#define HD 64
#define GD 192
#define TL 15
#define NHEADS 4
#define OUTD 32
#define TPB 16       // trees per treelstm block
#define CSCHUNK 160  // colstat stage-1 blocks

typedef unsigned short ushort_t;
typedef __attribute__((ext_vector_type(8))) short bf16x8;
typedef __attribute__((ext_vector_type(4))) float f32x4;

__device__ __forceinline__ ushort_t f2bf(float x) {
    __hip_bfloat16 h = __float2bfloat16(x);
    return *reinterpret_cast<ushort_t*>(&h);
}
__device__ __forceinline__ float fsig(float x) {
    return __builtin_amdgcn_rcpf(1.0f + __expf(-x));
}
__device__ __forceinline__ float ftanh(float x) {
    float e = __expf(-2.0f * fabsf(x));
    float t = 1.0f - 2.0f * e * __builtin_amdgcn_rcpf(1.0f + e);
    return copysignf(t, x);
}
__device__ __forceinline__ bf16x8 pack8(float4 lo, float4 hi) {
    bf16x8 a;
    a[0] = (short)f2bf(lo.x); a[1] = (short)f2bf(lo.y);
    a[2] = (short)f2bf(lo.z); a[3] = (short)f2bf(lo.w);
    a[4] = (short)f2bf(hi.x); a[5] = (short)f2bf(hi.y);
    a[6] = (short)f2bf(hi.z); a[7] = (short)f2bf(hi.w);
    return a;
}

// ---------------- setup: weight packing + attn folding + cnt zeroing ----------------
// B-frag for mfma_f32_16x16x32_bf16: lane l holds B[k=(l>>4)*8+j][n0+(l&15)], j=0..7
__global__ __launch_bounds__(256) void setup_kernel(
    const float* __restrict__ W_iou, const float* __restrict__ U_f_W,
    const float* __restrict__ U_iou, const float* __restrict__ Wt,
    const float* __restrict__ Wfc, const float* __restrict__ attn_l,
    const float* __restrict__ attn_r,
    ushort_t* __restrict__ Wb_iou, ushort_t* __restrict__ Wb_f,
    ushort_t* __restrict__ Wb_u, float* __restrict__ B_lr,
    int* __restrict__ cnt, int N)
{
    __shared__ float A_s[8][HD];
    const int blk = blockIdx.x;
    const int tid = threadIdx.x;
    if (blk < 160) {
        int idx = blk * 256 + tid;               // [0, 40960)
        if (idx < 24576) {                       // W_iou: 4kt x 12nt
            int j = idx & 7, l = (idx >> 3) & 63, f = idx >> 9;
            int kt = f / 12, nt = f % 12;
            int k = kt * 32 + ((l >> 4) * 8) + j;
            int nn = nt * 16 + (l & 15);
            float v = (k < XD) ? W_iou[nn * XD + k] : 0.f;
            Wb_iou[idx] = f2bf(v);
        } else if (idx < 24576 + 4096) {         // U_f_W: 2kt x 4nt
            int t = idx - 24576;
            int j = t & 7, l = (t >> 3) & 63, f = t >> 9;
            int kt = f >> 2, nt = f & 3;
            int k = kt * 32 + ((l >> 4) * 8) + j;
            int nn = nt * 16 + (l & 15);
            Wb_f[t] = f2bf(U_f_W[nn * HD + k]);
        } else {                                  // U_iou: 2kt x 12nt
            int t = idx - 24576 - 4096;
            int j = t & 7, l = (t >> 3) & 63, f = t >> 9;
            int kt = f / 12, nt = f % 12;
            int k = kt * 32 + ((l >> 4) * 8) + j;
            int g = nt * 16 + (l & 15);
            Wb_u[t] = f2bf(U_iou[g * HD + k]);
        }
    } else if (blk == 160) {
        // fold attn into projection: B_lr[q][x], q=0..3 -> el, 4..7 -> er
        for (int o = tid; o < 8 * HD; o += 256) {
            int q = o >> 6, c = o & 63;
            int h = q & 3;
            const float* attn = (q < 4) ? attn_l : attn_r;
            float s = 0.f;
            #pragma unroll 4
            for (int oo = 0; oo < OUTD; ++oo)
                s = fmaf(attn[h * OUTD + oo], Wfc[(h * OUTD + oo) * HD + c], s);
            A_s[q][c] = s;
        }
        __syncthreads();
        for (int o = tid; o < 8 * XD; o += 256) {
            int q = o / XD, x = o - q * XD;
            float s = 0.f;
            #pragma unroll 4
            for (int c = 0; c < HD; ++c)
                s = fmaf(A_s[q][c], Wt[c * XD + x], s);
            B_lr[o] = s;
        }
    } else {
        int i = (blk - 161) * 256 + tid;
        if (i < N) cnt[i] = 0;
    }
}

// ---------------- TreeLSTM fused (leaves + forget + root), pipelined, 16 trees/block ----------------
__global__ __launch_bounds__(256) void treelstm_fused(
    const float* __restrict__ ast_x, const float* __restrict__ c_init,
    const ushort_t* __restrict__ Wb_iou, const ushort_t* __restrict__ Wb_f,
    const ushort_t* __restrict__ Wb_u, const float* __restrict__ b_iou,
    const float* __restrict__ U_f_b, float* __restrict__ h_root, int Ntrees)
{
    __shared__ __align__(16) ushort_t xsb[2][16][136];  // bf16 X, double-buffered
    __shared__ __align__(16) ushort_t hlb[16][72];      // bf16 h_leaf
    __shared__ __align__(16) ushort_t htb[16][72];      // bf16 h_tild (per tree)
    __shared__ float credb[16][68];                     // f32 c_red (per tree)

    const int tid = threadIdx.x;
    const int lane = tid & 63;
    const int w = tid >> 6;
    const int arow = lane & 15;
    const int kgrp = lane >> 4;
    const int h = w * 16 + arow;
    const int base = blockIdx.x * TPB;

    const float bi = b_iou[h], bo = b_iou[64 + h], bu = b_iou[128 + h];
    const float fb = U_f_b[h];

    // persistent B fragments
    bf16x8 Bl[12];
    #pragma unroll
    for (int kt = 0; kt < 4; ++kt)
        #pragma unroll
        for (int j = 0; j < 3; ++j)
            Bl[kt * 3 + j] = *(const bf16x8*)(Wb_iou + (((size_t)kt * 12 + (w + 4 * j)) * 64 + lane) * 8);
    bf16x8 Bf[2];
    #pragma unroll
    for (int kt = 0; kt < 2; ++kt)
        Bf[kt] = *(const bf16x8*)(Wb_f + (((size_t)kt * 4 + w) * 64 + lane) * 8);

    // staging mapping: thread -> (row sr, 8-col chunk sc)
    const int sr = tid >> 4;
    const int sc = tid & 15;
    const bool sactive = (sr < TL) && (sc < 13);

    // zero-fill pad regions of both buffers once (cols 104..127 all rows; row 15 cols 0..103)
    for (int b = 0; b < 2; ++b) {
        for (int i = tid; i < 16 * 24; i += 256) {
            int r = i / 24, rem = i - r * 24;
            xsb[b][r][104 + rem] = 0;
        }
        for (int i = tid; i < 104; i += 256) xsb[b][15][i] = 0;
    }

    // prologue: stage tree 0
    float4 g0 = {0,0,0,0}, g1 = {0,0,0,0};
    if (sactive) {
        const float* xrow = ast_x + ((size_t)base * 16 + 1 + sr) * XD + sc * 8;
        g0 = *(const float4*)xrow;
        if (sc < 12) g1 = *(const float4*)(xrow + 4);
    }
    float cb4[4];
    {
        const float* cbp = c_init + ((size_t)base * 16 + 1) * HD;
        #pragma unroll
        for (int r = 0; r < 4; ++r) {
            int t = kgrp * 4 + r;
            cb4[r] = (t < TL) ? cbp[t * HD + h] : 0.f;
        }
    }
    if (sactive) *(bf16x8*)&xsb[0][sr][sc * 8] = pack8(g0, g1);
    __syncthreads();

    int cur = 0;
    for (int tt = 0; tt < TPB; ++tt) {
        const int n = base + tt;
        // prefetch next tree's X + c_init into registers (latency hides under compute)
        float4 p0 = {0,0,0,0}, p1 = {0,0,0,0};
        float cbn[4] = {0.f, 0.f, 0.f, 0.f};
        if (tt < TPB - 1) {
            if (sactive) {
                const float* xrow = ast_x + ((size_t)(n + 1) * 16 + 1 + sr) * XD + sc * 8;
                p0 = *(const float4*)xrow;
                if (sc < 12) p1 = *(const float4*)(xrow + 4);
            }
            const float* cbp = c_init + ((size_t)(n + 1) * 16 + 1) * HD;
            #pragma unroll
            for (int r = 0; r < 4; ++r) {
                int t = kgrp * 4 + r;
                cbn[r] = (t < TL) ? cbp[t * HD + h] : 0.f;
            }
        }

        // leaf GEMM: wave w owns ntiles {w, w+4, w+8} -> (i,o,u) for same h per lane
        f32x4 a0 = {0,0,0,0}, a1 = {0,0,0,0}, a2 = {0,0,0,0};
        #pragma unroll
        for (int kt = 0; kt < 4; ++kt) {
            bf16x8 a = *(const bf16x8*)&xsb[cur][arow][kt * 32 + kgrp * 8];
            a0 = __builtin_amdgcn_mfma_f32_16x16x32_bf16(a, Bl[kt * 3 + 0], a0, 0, 0, 0);
            a1 = __builtin_amdgcn_mfma_f32_16x16x32_bf16(a, Bl[kt * 3 + 1], a1, 0, 0, 0);
            a2 = __builtin_amdgcn_mfma_f32_16x16x32_bf16(a, Bl[kt * 3 + 2], a2, 0, 0, 0);
        }

        // leaf elementwise in registers
        float cl[4];
        float hsum = 0.f;
        #pragma unroll
        for (int r = 0; r < 4; ++r) {
            int t = kgrp * 4 + r;
            float hl = 0.f, c = 0.f;
            if (t < TL) {
                float i_ = a0[r] + bi, o_ = a1[r] + bo, u_ = a2[r] + bu;
                c = fsig(i_) * ftanh(u_) + cb4[r];
                hl = fsig(o_) * ftanh(c);
            }
            cl[r] = c;
            hsum += hl;
            hlb[t][h] = f2bf(hl);
        }
        __syncthreads();   // B2: hlb ready

        // forget GEMM (F fragment layout == c_leaf register layout)
        f32x4 fa = {0,0,0,0};
        #pragma unroll
        for (int kt = 0; kt < 2; ++kt) {
            bf16x8 a = *(const bf16x8*)&hlb[arow][kt * 32 + kgrp * 8];
            fa = __builtin_amdgcn_mfma_f32_16x16x32_bf16(a, Bf[kt], fa, 0, 0, 0);
        }
        float credsum = 0.f;
        #pragma unroll
        for (int r = 0; r < 4; ++r) {
            int t = kgrp * 4 + r;
            if (t < TL) credsum += fsig(fa[r] + fb) * cl[r];
        }
        hsum += __shfl_xor(hsum, 16);       hsum += __shfl_xor(hsum, 32);
        credsum += __shfl_xor(credsum, 16); credsum += __shfl_xor(credsum, 32);
        if (kgrp == 0) {
            htb[tt][h] = f2bf(hsum);
            credb[tt][h] = credsum;
        }

        // write prefetched tree into the other buffer (safe: nobody reads it now)
        if (tt < TPB - 1) {
            if (sactive) *(bf16x8*)&xsb[cur ^ 1][sr][sc * 8] = pack8(p0, p1);
            #pragma unroll
            for (int r = 0; r < 4; ++r) cb4[r] = cbn[r];
        }
        __syncthreads();   // B1: xs[next] ready; hlb reads done
        cur ^= 1;
    }

    // root GEMM: [16 trees, 64] @ [64,192], A = htb
    f32x4 r0 = {0,0,0,0}, r1 = {0,0,0,0}, r2 = {0,0,0,0};
    #pragma unroll
    for (int kt = 0; kt < 2; ++kt) {
        bf16x8 a = *(const bf16x8*)&htb[arow][kt * 32 + kgrp * 8];
        bf16x8 b0 = *(const bf16x8*)(Wb_u + (((size_t)kt * 12 + w)     * 64 + lane) * 8);
        bf16x8 b1 = *(const bf16x8*)(Wb_u + (((size_t)kt * 12 + w + 4) * 64 + lane) * 8);
        bf16x8 b2 = *(const bf16x8*)(Wb_u + (((size_t)kt * 12 + w + 8) * 64 + lane) * 8);
        r0 = __builtin_amdgcn_mfma_f32_16x16x32_bf16(a, b0, r0, 0, 0, 0);
        r1 = __builtin_amdgcn_mfma_f32_16x16x32_bf16(a, b1, r1, 0, 0, 0);
        r2 = __builtin_amdgcn_mfma_f32_16x16x32_bf16(a, b2, r2, 0, 0, 0);
    }
    #pragma unroll
    for (int r = 0; r < 4; ++r) {
        int m = kgrp * 4 + r;   // tree index within block
        float c = fsig(r0[r] + bi) * ftanh(r2[r] + bu) + credb[m][h];
        h_root[(size_t)(base + m) * HD + h] = fsig(r1[r] + bo) * ftanh(c);
    }
    (void)Ntrees;
}

// ---------------- el/er via folded projection ----------------
__global__ __launch_bounds__(256) void elr_kernel(
    const float* __restrict__ cfg_type, const float* __restrict__ B_lr,
    float* __restrict__ el, float* __restrict__ er, int N)
{
    __shared__ float xs[64 * XD];
    __shared__ float Bs[8 * XD];
    const int tid = threadIdx.x;
    const int base = blockIdx.x * 64;
    for (int i = tid; i < 8 * XD; i += 256) Bs[i] = B_lr[i];
    const size_t goff = (size_t)base * XD;
    long lim = (long)N * XD - (long)goff;
    if (lim > 64 * XD) lim = 64 * XD;
    for (int i = tid; i < lim; i += 256) xs[i] = cfg_type[goff + i];
    __syncthreads();
    for (int o = tid; o < 512; o += 256) {
        int r = o >> 3, q = o & 7;
        int node = base + r;
        if (node < N) {
            float s = 0.f;
            #pragma unroll 4
            for (int k = 0; k < XD; ++k)
                s = fmaf(xs[r * XD + k], Bs[q * XD + k], s);
            ((q < 4) ? el : er)[(size_t)node * NHEADS + (q & 3)] = s;
        }
    }
}

// ---------------- CSR build ----------------
__global__ void count_kernel(const int* __restrict__ dst, int* __restrict__ cnt, int E) {
    for (int e = blockIdx.x * blockDim.x + threadIdx.x; e < E; e += gridDim.x * blockDim.x)
        atomicAdd(&cnt[dst[e]], 1);
}

__global__ __launch_bounds__(1024) void scan_kernel(
    const int* __restrict__ cnt, int* __restrict__ offs, int* __restrict__ cursor, int N)
{
    __shared__ int part[1024];
    const int tid = threadIdx.x;
    const int per = (N + 1023) >> 10;
    int begin = tid * per;
    int end = begin + per; if (end > N) end = N;
    int s = 0;
    for (int i = begin; i < end && i < N; ++i) s += cnt[i];
    part[tid] = s;
    __syncthreads();
    for (int off = 1; off < 1024; off <<= 1) {
        int t = (tid >= off) ? part[tid - off] : 0;
        __syncthreads();
        part[tid] += t;
        __syncthreads();
    }
    int run = part[tid] - s;
    for (int i = begin; i < end && i < N; ++i) {
        offs[i] = run; cursor[i] = run; run += cnt[i];
    }
    if (tid == 1023) offs[N] = part[1023];
}

__global__ void fill_kernel(const int* __restrict__ src, const int* __restrict__ dst,
                            int* __restrict__ cursor, int* __restrict__ csr_src, int E) {
    for (int e = blockIdx.x * blockDim.x + threadIdx.x; e < E; e += gridDim.x * blockDim.x) {
        int p = atomicAdd(&cursor[dst[e]], 1);
        csr_src[p] = src[e];
    }
}

// ---------------- per-dst edge softmax + aggregation + W_out: 4 dst/block, 1 wave each ----------------
// NOTE: no __syncthreads anywhere (waves are independent; barrier counts would diverge).
// Within-wave LDS producer/consumer ordering is program-order + compiler lgkmcnt.
__global__ __launch_bounds__(256) void agg_kernel(
    const float* __restrict__ h_root, const float* __restrict__ el,
    const float* __restrict__ er, const int* __restrict__ offs,
    const int* __restrict__ csr_src, const float* __restrict__ W_out,
    const float* __restrict__ bias_g, float* __restrict__ rst, int N)
{
    const int wid = threadIdx.x >> 6;
    const int lane = threadIdx.x & 63;
    const int n = blockIdx.x * 4 + wid;
    if (n >= N) return;
    __shared__ int s_src[4][64];
    __shared__ __align__(16) float s_ez[4][64][NHEADS];
    __shared__ float s_agg[4][NHEADS][HD];

    const int beg = offs[n];
    const int deg = offs[n + 1] - beg;
    const float4 erv = *(const float4*)&er[(size_t)n * NHEADS];

    float acc[NHEADS] = {0.f, 0.f, 0.f, 0.f};
    float ps[NHEADS] = {0.f, 0.f, 0.f, 0.f};

    if (deg <= 64) {
        int srcj = 0;
        float v[NHEADS] = {-INFINITY, -INFINITY, -INFINITY, -INFINITY};
        if (lane < deg) {
            srcj = csr_src[beg + lane];
            float4 elv = *(const float4*)&el[(size_t)srcj * NHEADS];
            float t0 = elv.x + erv.x, t1 = elv.y + erv.y;
            float t2 = elv.z + erv.z, t3 = elv.w + erv.w;
            v[0] = t0 > 0.f ? t0 : 0.2f * t0;
            v[1] = t1 > 0.f ? t1 : 0.2f * t1;
            v[2] = t2 > 0.f ? t2 : 0.2f * t2;
            v[3] = t3 > 0.f ? t3 : 0.2f * t3;
        }
        float mx[NHEADS];
        #pragma unroll
        for (int hh = 0; hh < NHEADS; ++hh) {
            mx[hh] = v[hh];
            for (int off = 1; off < 64; off <<= 1)
                mx[hh] = fmaxf(mx[hh], __shfl_xor(mx[hh], off));
        }
        float ez[NHEADS] = {0.f, 0.f, 0.f, 0.f};
        if (lane < deg) {
            #pragma unroll
            for (int hh = 0; hh < NHEADS; ++hh) { ez[hh] = __expf(v[hh] - mx[hh]); ps[hh] = ez[hh]; }
        }
        s_src[wid][lane] = srcj;
        *(float4*)&s_ez[wid][lane][0] = make_float4(ez[0], ez[1], ez[2], ez[3]);
        #pragma unroll 8
        for (int jj = 0; jj < deg; ++jj) {
            const float hv = h_root[(size_t)s_src[wid][jj] * HD + lane];
            #pragma unroll
            for (int hh = 0; hh < NHEADS; ++hh) acc[hh] = fmaf(s_ez[wid][jj][hh], hv, acc[hh]);
        }
    } else {
        float mx[NHEADS] = {-INFINITY, -INFINITY, -INFINITY, -INFINITY};
        for (int j = lane; j < deg; j += 64) {
            const int src = csr_src[beg + j];
            float4 elv = *(const float4*)&el[(size_t)src * NHEADS];
            float t[4] = {elv.x + erv.x, elv.y + erv.y, elv.z + erv.z, elv.w + erv.w};
            #pragma unroll
            for (int hh = 0; hh < NHEADS; ++hh) {
                float x = t[hh] > 0.f ? t[hh] : 0.2f * t[hh];
                mx[hh] = fmaxf(mx[hh], x);
            }
        }
        #pragma unroll
        for (int hh = 0; hh < NHEADS; ++hh)
            for (int off = 1; off < 64; off <<= 1)
                mx[hh] = fmaxf(mx[hh], __shfl_xor(mx[hh], off));
        for (int j0 = 0; j0 < deg; j0 += 64) {
            const int j = j0 + lane;
            float ezl[NHEADS] = {0.f, 0.f, 0.f, 0.f};
            int srcj = 0;
            if (j < deg) {
                srcj = csr_src[beg + j];
                float4 elv = *(const float4*)&el[(size_t)srcj * NHEADS];
                float t[4] = {elv.x + erv.x, elv.y + erv.y, elv.z + erv.z, elv.w + erv.w};
                #pragma unroll
                for (int hh = 0; hh < NHEADS; ++hh) {
                    float x = t[hh] > 0.f ? t[hh] : 0.2f * t[hh];
                    float e = __expf(x - mx[hh]);
                    ezl[hh] = e; ps[hh] += e;
                }
            }
            s_src[wid][lane] = srcj;
            *(float4*)&s_ez[wid][lane][0] = make_float4(ezl[0], ezl[1], ezl[2], ezl[3]);
            const int cnt2 = min(64, deg - j0);
            #pragma unroll 8
            for (int jj = 0; jj < cnt2; ++jj) {
                const float hv = h_root[(size_t)s_src[wid][jj] * HD + lane];
                #pragma unroll
                for (int hh = 0; hh < NHEADS; ++hh) acc[hh] = fmaf(s_ez[wid][jj][hh], hv, acc[hh]);
            }
        }
    }

    #pragma unroll
    for (int hh = 0; hh < NHEADS; ++hh)
        for (int off = 1; off < 64; off <<= 1)
            ps[hh] += __shfl_xor(ps[hh], off);

    #pragma unroll
    for (int hh = 0; hh < NHEADS; ++hh) {
        float inv = (deg > 0) ? 1.f / ps[hh] : 0.f;
        s_agg[wid][hh][lane] = acc[hh] * inv;
    }

    #pragma unroll
    for (int idx = lane; idx < NHEADS * OUTD; idx += 64) {
        const int hh = idx >> 5, o = idx & 31;
        float s = bias_g[idx];
        #pragma unroll 4
        for (int c = 0; c < HD; ++c) s = fmaf(s_agg[wid][hh][c], W_out[o * HD + c], s);
        rst[(size_t)n * 128 + idx] = s;
    }
}

// ---------------- axis-0 softmax stats, stage 1: coalesced chunk partials ----------------
__global__ __launch_bounds__(256) void colstat1(
    const float* __restrict__ rst, float* __restrict__ pm,
    float* __restrict__ psum, int N)
{
    const int blk = blockIdx.x;
    const int per = (N + CSCHUNK - 1) / CSCHUNK;
    const int lo = blk * per;
    const int hi = min(lo + per, N);
    const int c = threadIdx.x & 127, half = threadIdx.x >> 7;
    __shared__ float red[256];
    __shared__ float cmx[128];
    float m = -INFINITY;
    for (int r = lo + half; r < hi; r += 2)
        m = fmaxf(m, rst[(size_t)r * 128 + c]);
    red[threadIdx.x] = m;
    __syncthreads();
    if (threadIdx.x < 128)
        cmx[threadIdx.x] = fmaxf(red[threadIdx.x], red[threadIdx.x + 128]);
    __syncthreads();
    const float mm = cmx[c];
    float s = 0.f;
    for (int r = lo + half; r < hi; r += 2)
        s += __expf(rst[(size_t)r * 128 + c] - mm);
    red[threadIdx.x] = s;
    __syncthreads();
    if (threadIdx.x < 128) {
        pm[blk * 128 + threadIdx.x] = cmx[threadIdx.x];
        psum[blk * 128 + threadIdx.x] = red[threadIdx.x] + red[threadIdx.x + 128];
    }
}

// ---------------- axis-0 softmax stats, stage 2: combine chunk partials ----------------
__global__ __launch_bounds__(128) void colstat2(
    const float* __restrict__ pm, const float* __restrict__ psum,
    float* __restrict__ colmax, float* __restrict__ colsum)
{
    const int c = threadIdx.x;
    float m = -INFINITY;
    for (int b = 0; b < CSCHUNK; ++b) m = fmaxf(m, pm[b * 128 + c]);
    float s = 0.f;
    for (int b = 0; b < CSCHUNK; ++b) s += psum[b * 128 + c] * __expf(pm[b * 128 + c] - m);
    colmax[c] = m; colsum[c] = s;
}

// ---------------- softmax + folded classifier ----------------
__global__ __launch_bounds__(256) void final_kernel(
    const float* __restrict__ rst, const float* __restrict__ colmax,
    const float* __restrict__ colsum, const float* __restrict__ W1,
    const float* __restrict__ b1, const float* __restrict__ W2,
    const float* __restrict__ b2, float* __restrict__ out, int N)
{
    __shared__ float M[2][OUTD];
    __shared__ float bv[2];
    __shared__ float cm[128], cs[128];
    const int tid = threadIdx.x;
    if (tid < 64) {
        const int r = tid >> 5, o = tid & 31;
        float s = 0.f;
        #pragma unroll
        for (int k = 0; k < 16; ++k) s = fmaf(W2[r * 16 + k], W1[k * 32 + o], s);
        M[r][o] = s;
    }
    if (tid < 2) {
        float s = b2[tid];
        #pragma unroll
        for (int k = 0; k < 16; ++k) s = fmaf(b1[k], W2[tid * 16 + k], s);
        bv[tid] = s;
    }
    if (tid < 128) { cm[tid] = colmax[tid]; cs[tid] = colsum[tid]; }
    __syncthreads();
    for (int row = blockIdx.x * 256 + tid; row < N * 4; row += gridDim.x * 256) {
        const int n = row >> 2, h = row & 3;
        const float* r = rst + (size_t)n * 128 + h * 32;
        float a0 = bv[0], a1 = bv[1];
        #pragma unroll 4
        for (int o = 0; o < OUTD; ++o) {
            const int c = h * 32 + o;
            float p = __expf(r[o] - cm[c]) / cs[c];
            a0 = fmaf(p, M[0][o], a0);
            a1 = fmaf(p, M[1][o], a1);
        }
        out[(size_t)row * 2 + 0] = a0;
        out[(size_t)row * 2 + 1] = a1;
    }
}

extern "C" void kernel_launch(void* const* d_in, const int* in_sizes, int n_in,
                              void* d_out, int out_size, void* d_ws, size_t ws_size,
                              hipStream_t stream) {
    const float* ast_x   = (const float*)d_in[0];
    const float* c_init  = (const float*)d_in[1];
    const float* cfg_type= (const float*)d_in[2];
    const float* W_iou   = (const float*)d_in[3];
    const float* b_iou   = (const float*)d_in[4];
    const float* U_iou   = (const float*)d_in[5];
    const float* U_f_W   = (const float*)d_in[6];
    const float* U_f_b   = (const float*)d_in[7];
    const float* Wt      = (const float*)d_in[8];
    const float* Wfc     = (const float*)d_in[9];
    const float* attn_l  = (const float*)d_in[10];
    const float* attn_r  = (const float*)d_in[11];
    const float* W_out   = (const float*)d_in[12];
    const float* bias_g  = (const float*)d_in[13];
    const float* W1      = (const float*)d_in[14];
    const float* b1      = (const float*)d_in[15];
    const float* W2      = (const float*)d_in[16];
    const float* b2      = (const float*)d_in[17];
    const int* edge_src  = (const int*)d_in[18];
    const int* edge_dst  = (const int*)d_in[19];

    const int N = in_sizes[2] / XD;      // 20000
    const int E = in_sizes[18];          // 640000
    (void)n_in; (void)out_size; (void)ws_size;

    char* w = (char*)d_ws;
    auto take = [&](size_t bytes) { char* p = w; w += (bytes + 255) & ~(size_t)255; return p; };
    float*    h_root  = (float*)take((size_t)N * HD * 4);
    float*    el      = (float*)take((size_t)N * NHEADS * 4);
    float*    er      = (float*)take((size_t)N * NHEADS * 4);
    int*      cnt     = (int*)take((size_t)N * 4);
    int*      offs    = (int*)take(((size_t)N + 1) * 4);
    int*      cursor  = (int*)take((size_t)N * 4);
    int*      csr_src = (int*)take((size_t)E * 4);
    float*    rst     = (float*)take((size_t)N * 128 * 4);
    float*    colmax  = (float*)take(128 * 4);
    float*    colsum  = (float*)take(128 * 4);
    ushort_t* Wb_iou  = (ushort_t*)take(24576 * 2);
    ushort_t* Wb_f    = (ushort_t*)take(4096 * 2);
    ushort_t* Wb_u    = (ushort_t*)take(12288 * 2);
    float*    B_lr    = (float*)take(800 * 4);
    float*    pm      = (float*)take((size_t)CSCHUNK * 128 * 4);
    float*    psum    = (float*)take((size_t)CSCHUNK * 128 * 4);

    const int zeroBlocks = (N + 255) / 256;
    setup_kernel<<<161 + zeroBlocks, 256, 0, stream>>>(
        W_iou, U_f_W, U_iou, Wt, Wfc, attn_l, attn_r,
        Wb_iou, Wb_f, Wb_u, B_lr, cnt, N);
    count_kernel<<<1024, 256, 0, stream>>>(edge_dst, cnt, E);
    scan_kernel<<<1, 1024, 0, stream>>>(cnt, offs, cursor, N);
    fill_kernel<<<1024, 256, 0, stream>>>(edge_src, edge_dst, cursor, csr_src, E);
    treelstm_fused<<<(N + TPB - 1) / TPB, 256, 0, stream>>>(
        ast_x, c_init, Wb_iou, Wb_f, Wb_u, b_iou, U_f_b, h_root, N);
    elr_kernel<<<(N + 63) / 64, 256, 0, stream>>>(cfg_type, B_lr, el, er, N);
    agg_kernel<<<(N + 3) / 4, 256, 0, stream>>>(h_root, el, er, offs, csr_src, W_out, bias_g, rst, N);
    colstat1<<<CSCHUNK, 256, 0, stream>>>(rst, pm, psum, N);
    colstat2<<<1, 128, 0, stream>>>(pm, psum, colmax, colsum);
    final_kernel<<<(N * 4 + 255) / 256, 256, 0, stream>>>(rst, colmax, colsum, W1, b1, W2, b2, (float*)d_out, N);
}

// Round 5
// 344.813 us; speedup vs baseline: 11.3717x; 1.0108x over previous
//
#include <hip/hip_runtime.h>
#include <hip/hip_bf16.h>
#include <math.h>

#define XD 100
#define HD 64
#define GD 192
#define TL 15
#define NHEADS 4
#define OUTD 32
#define TPB 8        // trees per treelstm block
#define CSCHUNK 160  // colstat stage-1 blocks

typedef unsigned short ushort_t;
typedef __attribute__((ext_vector_type(8))) short bf16x8;
typedef __attribute__((ext_vector_type(4))) float f32x4;

__device__ __forceinline__ ushort_t f2bf(float x) {
    __hip_bfloat16 h = __float2bfloat16(x);
    return *reinterpret_cast<ushort_t*>(&h);
}
__device__ __forceinline__ float fsig(float x) {
    return __builtin_amdgcn_rcpf(1.0f + __expf(-x));
}
__device__ __forceinline__ float ftanh(float x) {
    float e = __expf(-2.0f * fabsf(x));
    float t = 1.0f - 2.0f * e * __builtin_amdgcn_rcpf(1.0f + e);
    return copysignf(t, x);
}
__device__ __forceinline__ bf16x8 pack8(float4 lo, float4 hi) {
    bf16x8 a;
    a[0] = (short)f2bf(lo.x); a[1] = (short)f2bf(lo.y);
    a[2] = (short)f2bf(lo.z); a[3] = (short)f2bf(lo.w);
    a[4] = (short)f2bf(hi.x); a[5] = (short)f2bf(hi.y);
    a[6] = (short)f2bf(hi.z); a[7] = (short)f2bf(hi.w);
    return a;
}

// ---------------- setup: weight packing + attn folding + cnt zeroing ----------------
// B-frag for mfma_f32_16x16x32_bf16: lane l holds B[k=(l>>4)*8+j][n0+(l&15)], j=0..7
__global__ __launch_bounds__(256) void setup_kernel(
    const float* __restrict__ W_iou, const float* __restrict__ U_f_W,
    const float* __restrict__ U_iou, const float* __restrict__ Wt,
    const float* __restrict__ Wfc, const float* __restrict__ attn_l,
    const float* __restrict__ attn_r,
    ushort_t* __restrict__ Wb_iou, ushort_t* __restrict__ Wb_f,
    ushort_t* __restrict__ Wb_u, float* __restrict__ B_lr,
    int* __restrict__ cnt, int N)
{
    __shared__ float A_s[8][HD];
    const int blk = blockIdx.x;
    const int tid = threadIdx.x;
    if (blk < 160) {
        int idx = blk * 256 + tid;               // [0, 40960)
        if (idx < 24576) {                       // W_iou: 4kt x 12nt
            int j = idx & 7, l = (idx >> 3) & 63, f = idx >> 9;
            int kt = f / 12, nt = f % 12;
            int k = kt * 32 + ((l >> 4) * 8) + j;
            int nn = nt * 16 + (l & 15);
            float v = (k < XD) ? W_iou[nn * XD + k] : 0.f;
            Wb_iou[idx] = f2bf(v);
        } else if (idx < 24576 + 4096) {         // U_f_W: 2kt x 4nt
            int t = idx - 24576;
            int j = t & 7, l = (t >> 3) & 63, f = t >> 9;
            int kt = f >> 2, nt = f & 3;
            int k = kt * 32 + ((l >> 4) * 8) + j;
            int nn = nt * 16 + (l & 15);
            Wb_f[t] = f2bf(U_f_W[nn * HD + k]);
        } else {                                  // U_iou: 2kt x 12nt
            int t = idx - 24576 - 4096;
            int j = t & 7, l = (t >> 3) & 63, f = t >> 9;
            int kt = f / 12, nt = f % 12;
            int k = kt * 32 + ((l >> 4) * 8) + j;
            int g = nt * 16 + (l & 15);
            Wb_u[t] = f2bf(U_iou[g * HD + k]);
        }
    } else if (blk == 160) {
        // fold attn into projection: B_lr[q][x], q=0..3 -> el, 4..7 -> er
        for (int o = tid; o < 8 * HD; o += 256) {
            int q = o >> 6, c = o & 63;
            int h = q & 3;
            const float* attn = (q < 4) ? attn_l : attn_r;
            float s = 0.f;
            #pragma unroll 4
            for (int oo = 0; oo < OUTD; ++oo)
                s = fmaf(attn[h * OUTD + oo], Wfc[(h * OUTD + oo) * HD + c], s);
            A_s[q][c] = s;
        }
        __syncthreads();
        for (int o = tid; o < 8 * XD; o += 256) {
            int q = o / XD, x = o - q * XD;
            float s = 0.f;
            #pragma unroll 4
            for (int c = 0; c < HD; ++c)
                s = fmaf(A_s[q][c], Wt[c * XD + x], s);
            B_lr[o] = s;
        }
    } else {
        int i = (blk - 161) * 256 + tid;
        if (i < N) cnt[i] = 0;
    }
}

// ---------------- TreeLSTM fused: 8 trees/block, ONE barrier per tree ----------------
__global__ __launch_bounds__(256) void treelstm_fused(
    const float* __restrict__ ast_x, const float* __restrict__ c_init,
    const ushort_t* __restrict__ Wb_iou, const ushort_t* __restrict__ Wb_f,
    const ushort_t* __restrict__ Wb_u, const float* __restrict__ b_iou,
    const float* __restrict__ U_f_b, float* __restrict__ h_root, int Ntrees)
{
    __shared__ __align__(16) ushort_t xsb[2][16][136];  // bf16 X, double-buffered
    __shared__ __align__(16) ushort_t hlb[2][16][72];   // bf16 h_leaf, double-buffered
    __shared__ __align__(16) ushort_t htb[16][72];      // bf16 h_tild (rows TPB..15 zero)
    __shared__ float credb[TPB][68];                    // f32 c_red per tree

    const int tid = threadIdx.x;
    const int lane = tid & 63;
    const int w = tid >> 6;
    const int arow = lane & 15;
    const int kgrp = lane >> 4;
    const int h = w * 16 + arow;
    const int base = blockIdx.x * TPB;

    const float bi = b_iou[h], bo = b_iou[64 + h], bu = b_iou[128 + h];
    const float fb = U_f_b[h];

    // persistent B fragments
    bf16x8 Bl[12];
    #pragma unroll
    for (int kt = 0; kt < 4; ++kt)
        #pragma unroll
        for (int j = 0; j < 3; ++j)
            Bl[kt * 3 + j] = *(const bf16x8*)(Wb_iou + (((size_t)kt * 12 + (w + 4 * j)) * 64 + lane) * 8);
    bf16x8 Bf[2];
    #pragma unroll
    for (int kt = 0; kt < 2; ++kt)
        Bf[kt] = *(const bf16x8*)(Wb_f + (((size_t)kt * 4 + w) * 64 + lane) * 8);

    // staging mapping: thread -> (row sr, 8-col chunk sc)
    const int sr = tid >> 4;
    const int sc = tid & 15;
    const bool sactive = (sr < TL) && (sc < 13);

    // zero-fill pads once: xsb cols 104..127 + row 15; htb rows TPB..15
    for (int b = 0; b < 2; ++b) {
        for (int i = tid; i < 16 * 24; i += 256) {
            int r = i / 24, rem = i - r * 24;
            xsb[b][r][104 + rem] = 0;
        }
        for (int i = tid; i < 104; i += 256) xsb[b][15][i] = 0;
    }
    for (int i = tid; i < (16 - TPB) * 72; i += 256)
        htb[TPB + i / 72][i % 72] = 0;

    // prologue: stage tree 0
    float4 g0 = {0,0,0,0}, g1 = {0,0,0,0};
    if (sactive) {
        const float* xrow = ast_x + ((size_t)base * 16 + 1 + sr) * XD + sc * 8;
        g0 = *(const float4*)xrow;
        if (sc < 12) g1 = *(const float4*)(xrow + 4);
    }
    float cb4[4];
    {
        const float* cbp = c_init + ((size_t)base * 16 + 1) * HD;
        #pragma unroll
        for (int r = 0; r < 4; ++r) {
            int t = kgrp * 4 + r;
            cb4[r] = (t < TL) ? cbp[t * HD + h] : 0.f;
        }
    }
    if (sactive) *(bf16x8*)&xsb[0][sr][sc * 8] = pack8(g0, g1);
    __syncthreads();

    #pragma unroll 2
    for (int tt = 0; tt < TPB; ++tt) {
        const int p = tt & 1;
        const int n = base + tt;

        // prefetch next tree's X + c_init into registers
        float4 p0 = {0,0,0,0}, p1 = {0,0,0,0};
        float cbn[4] = {0.f, 0.f, 0.f, 0.f};
        if (tt < TPB - 1) {
            if (sactive) {
                const float* xrow = ast_x + ((size_t)(n + 1) * 16 + 1 + sr) * XD + sc * 8;
                p0 = *(const float4*)xrow;
                if (sc < 12) p1 = *(const float4*)(xrow + 4);
            }
            const float* cbp = c_init + ((size_t)(n + 1) * 16 + 1) * HD;
            #pragma unroll
            for (int r = 0; r < 4; ++r) {
                int t = kgrp * 4 + r;
                cbn[r] = (t < TL) ? cbp[t * HD + h] : 0.f;
            }
        }

        // leaf GEMM: wave w owns ntiles {w, w+4, w+8} -> (i,o,u) for same h per lane
        f32x4 a0 = {0,0,0,0}, a1 = {0,0,0,0}, a2 = {0,0,0,0};
        #pragma unroll
        for (int kt = 0; kt < 4; ++kt) {
            bf16x8 a = *(const bf16x8*)&xsb[p][arow][kt * 32 + kgrp * 8];
            a0 = __builtin_amdgcn_mfma_f32_16x16x32_bf16(a, Bl[kt * 3 + 0], a0, 0, 0, 0);
            a1 = __builtin_amdgcn_mfma_f32_16x16x32_bf16(a, Bl[kt * 3 + 1], a1, 0, 0, 0);
            a2 = __builtin_amdgcn_mfma_f32_16x16x32_bf16(a, Bl[kt * 3 + 2], a2, 0, 0, 0);
        }

        // leaf elementwise in registers; write bf16 h_leaf to hlb[p]
        float cl[4];
        float hsum = 0.f;
        #pragma unroll
        for (int r = 0; r < 4; ++r) {
            int t = kgrp * 4 + r;
            float hl = 0.f, c = 0.f;
            if (t < TL) {
                float i_ = a0[r] + bi, o_ = a1[r] + bo, u_ = a2[r] + bu;
                c = fsig(i_) * ftanh(u_) + cb4[r];
                hl = fsig(o_) * ftanh(c);
            }
            cl[r] = c;
            hsum += hl;
            hlb[p][t][h] = f2bf(hl);
        }

        // stage prefetched tree into the other X buffer (its readers synced 1 barrier ago)
        if (tt < TPB - 1) {
            if (sactive) *(bf16x8*)&xsb[p ^ 1][sr][sc * 8] = pack8(p0, p1);
            #pragma unroll
            for (int r = 0; r < 4; ++r) cb4[r] = cbn[r];
        }
        __syncthreads();   // single barrier: hlb[p] ready, xsb[p^1] ready

        // forget GEMM (F fragment layout == c_leaf register layout)
        f32x4 fa = {0,0,0,0};
        #pragma unroll
        for (int kt = 0; kt < 2; ++kt) {
            bf16x8 a = *(const bf16x8*)&hlb[p][arow][kt * 32 + kgrp * 8];
            fa = __builtin_amdgcn_mfma_f32_16x16x32_bf16(a, Bf[kt], fa, 0, 0, 0);
        }
        float credsum = 0.f;
        #pragma unroll
        for (int r = 0; r < 4; ++r) {
            int t = kgrp * 4 + r;
            if (t < TL) credsum += fsig(fa[r] + fb) * cl[r];
        }
        hsum += __shfl_xor(hsum, 16);       hsum += __shfl_xor(hsum, 32);
        credsum += __shfl_xor(credsum, 16); credsum += __shfl_xor(credsum, 32);
        if (kgrp == 0) {
            htb[tt][h] = f2bf(hsum);
            credb[tt][h] = credsum;
        }
    }
    __syncthreads();   // htb/credb complete

    // root GEMM: [16,64] @ [64,192] (rows TPB..15 are zero)
    f32x4 r0 = {0,0,0,0}, r1 = {0,0,0,0}, r2 = {0,0,0,0};
    #pragma unroll
    for (int kt = 0; kt < 2; ++kt) {
        bf16x8 a = *(const bf16x8*)&htb[arow][kt * 32 + kgrp * 8];
        bf16x8 b0 = *(const bf16x8*)(Wb_u + (((size_t)kt * 12 + w)     * 64 + lane) * 8);
        bf16x8 b1 = *(const bf16x8*)(Wb_u + (((size_t)kt * 12 + w + 4) * 64 + lane) * 8);
        bf16x8 b2 = *(const bf16x8*)(Wb_u + (((size_t)kt * 12 + w + 8) * 64 + lane) * 8);
        r0 = __builtin_amdgcn_mfma_f32_16x16x32_bf16(a, b0, r0, 0, 0, 0);
        r1 = __builtin_amdgcn_mfma_f32_16x16x32_bf16(a, b1, r1, 0, 0, 0);
        r2 = __builtin_amdgcn_mfma_f32_16x16x32_bf16(a, b2, r2, 0, 0, 0);
    }
    #pragma unroll
    for (int r = 0; r < 4; ++r) {
        int m = kgrp * 4 + r;   // tree index within block
        if (m < TPB) {
            float c = fsig(r0[r] + bi) * ftanh(r2[r] + bu) + credb[m][h];
            h_root[(size_t)(base + m) * HD + h] = fsig(r1[r] + bo) * ftanh(c);
        }
    }
    (void)Ntrees;
}

// ---------------- el/er via folded projection ----------------
__global__ __launch_bounds__(256) void elr_kernel(
    const float* __restrict__ cfg_type, const float* __restrict__ B_lr,
    float* __restrict__ el, float* __restrict__ er, int N)
{
    __shared__ float xs[64 * XD];
    __shared__ float Bs[8 * XD];
    const int tid = threadIdx.x;
    const int base = blockIdx.x * 64;
    for (int i = tid; i < 8 * XD; i += 256) Bs[i] = B_lr[i];
    const size_t goff = (size_t)base * XD;
    long lim = (long)N * XD - (long)goff;
    if (lim > 64 * XD) lim = 64 * XD;
    for (int i = tid; i < lim; i += 256) xs[i] = cfg_type[goff + i];
    __syncthreads();
    for (int o = tid; o < 512; o += 256) {
        int r = o >> 3, q = o & 7;
        int node = base + r;
        if (node < N) {
            float s = 0.f;
            #pragma unroll 4
            for (int k = 0; k < XD; ++k)
                s = fmaf(xs[r * XD + k], Bs[q * XD + k], s);
            ((q < 4) ? el : er)[(size_t)node * NHEADS + (q & 3)] = s;
        }
    }
}

// ---------------- CSR build ----------------
__global__ void count_kernel(const int* __restrict__ dst, int* __restrict__ cnt, int E) {
    for (int e = blockIdx.x * blockDim.x + threadIdx.x; e < E; e += gridDim.x * blockDim.x)
        atomicAdd(&cnt[dst[e]], 1);
}

__global__ __launch_bounds__(1024) void scan_kernel(
    const int* __restrict__ cnt, int* __restrict__ offs, int* __restrict__ cursor, int N)
{
    __shared__ int part[1024];
    const int tid = threadIdx.x;
    const int per = (N + 1023) >> 10;
    int begin = tid * per;
    int end = begin + per; if (end > N) end = N;
    int s = 0;
    for (int i = begin; i < end && i < N; ++i) s += cnt[i];
    part[tid] = s;
    __syncthreads();
    for (int off = 1; off < 1024; off <<= 1) {
        int t = (tid >= off) ? part[tid - off] : 0;
        __syncthreads();
        part[tid] += t;
        __syncthreads();
    }
    int run = part[tid] - s;
    for (int i = begin; i < end && i < N; ++i) {
        offs[i] = run; cursor[i] = run; run += cnt[i];
    }
    if (tid == 1023) offs[N] = part[1023];
}

__global__ void fill_kernel(const int* __restrict__ src, const int* __restrict__ dst,
                            int* __restrict__ cursor, int* __restrict__ csr_src, int E) {
    for (int e = blockIdx.x * blockDim.x + threadIdx.x; e < E; e += gridDim.x * blockDim.x) {
        int p = atomicAdd(&cursor[dst[e]], 1);
        csr_src[p] = src[e];
    }
}

// ---------------- per-dst edge softmax + aggregation + W_out: 4 dst/block, 1 wave each ----------------
// Max-subtraction dropped: |leaky(el+er)| < ~1 by construction, exp is safe and the
// normalized ratio is mathematically identical. No __syncthreads (independent waves).
__global__ __launch_bounds__(256) void agg_kernel(
    const float* __restrict__ h_root, const float* __restrict__ el,
    const float* __restrict__ er, const int* __restrict__ offs,
    const int* __restrict__ csr_src, const float* __restrict__ W_out,
    const float* __restrict__ bias_g, float* __restrict__ rst, int N)
{
    const int wid = threadIdx.x >> 6;
    const int lane = threadIdx.x & 63;
    const int n = blockIdx.x * 4 + wid;
    if (n >= N) return;
    __shared__ int s_src[4][64];
    __shared__ __align__(16) float s_ez[4][64][NHEADS];
    __shared__ float s_agg[4][NHEADS][HD];

    const int beg = offs[n];
    const int deg = offs[n + 1] - beg;
    const float4 erv = *(const float4*)&er[(size_t)n * NHEADS];

    float acc[NHEADS] = {0.f, 0.f, 0.f, 0.f};
    float ps[NHEADS] = {0.f, 0.f, 0.f, 0.f};

    if (deg <= 64) {
        int srcj = 0;
        float ez[NHEADS] = {0.f, 0.f, 0.f, 0.f};
        if (lane < deg) {
            srcj = csr_src[beg + lane];
            float4 elv = *(const float4*)&el[(size_t)srcj * NHEADS];
            float t0 = elv.x + erv.x, t1 = elv.y + erv.y;
            float t2 = elv.z + erv.z, t3 = elv.w + erv.w;
            t0 = t0 > 0.f ? t0 : 0.2f * t0;
            t1 = t1 > 0.f ? t1 : 0.2f * t1;
            t2 = t2 > 0.f ? t2 : 0.2f * t2;
            t3 = t3 > 0.f ? t3 : 0.2f * t3;
            ez[0] = __expf(t0); ez[1] = __expf(t1);
            ez[2] = __expf(t2); ez[3] = __expf(t3);
            #pragma unroll
            for (int hh = 0; hh < NHEADS; ++hh) ps[hh] = ez[hh];
        }
        s_src[wid][lane] = srcj;
        *(float4*)&s_ez[wid][lane][0] = make_float4(ez[0], ez[1], ez[2], ez[3]);
        #pragma unroll 8
        for (int jj = 0; jj < deg; ++jj) {
            const float hv = h_root[(size_t)s_src[wid][jj] * HD + lane];
            #pragma unroll
            for (int hh = 0; hh < NHEADS; ++hh) acc[hh] = fmaf(s_ez[wid][jj][hh], hv, acc[hh]);
        }
    } else {
        for (int j0 = 0; j0 < deg; j0 += 64) {
            const int j = j0 + lane;
            float ezl[NHEADS] = {0.f, 0.f, 0.f, 0.f};
            int srcj = 0;
            if (j < deg) {
                srcj = csr_src[beg + j];
                float4 elv = *(const float4*)&el[(size_t)srcj * NHEADS];
                float t[4] = {elv.x + erv.x, elv.y + erv.y, elv.z + erv.z, elv.w + erv.w};
                #pragma unroll
                for (int hh = 0; hh < NHEADS; ++hh) {
                    float x = t[hh] > 0.f ? t[hh] : 0.2f * t[hh];
                    float e = __expf(x);
                    ezl[hh] = e; ps[hh] += e;
                }
            }
            s_src[wid][lane] = srcj;
            *(float4*)&s_ez[wid][lane][0] = make_float4(ezl[0], ezl[1], ezl[2], ezl[3]);
            const int cnt2 = min(64, deg - j0);
            #pragma unroll 8
            for (int jj = 0; jj < cnt2; ++jj) {
                const float hv = h_root[(size_t)s_src[wid][jj] * HD + lane];
                #pragma unroll
                for (int hh = 0; hh < NHEADS; ++hh) acc[hh] = fmaf(s_ez[wid][jj][hh], hv, acc[hh]);
            }
        }
    }

    #pragma unroll
    for (int hh = 0; hh < NHEADS; ++hh)
        for (int off = 1; off < 64; off <<= 1)
            ps[hh] += __shfl_xor(ps[hh], off);

    #pragma unroll
    for (int hh = 0; hh < NHEADS; ++hh) {
        float inv = (deg > 0) ? 1.f / ps[hh] : 0.f;
        s_agg[wid][hh][lane] = acc[hh] * inv;
    }

    #pragma unroll
    for (int idx = lane; idx < NHEADS * OUTD; idx += 64) {
        const int hh = idx >> 5, o = idx & 31;
        float s = bias_g[idx];
        #pragma unroll 4
        for (int c = 0; c < HD; ++c) s = fmaf(s_agg[wid][hh][c], W_out[o * HD + c], s);
        rst[(size_t)n * 128 + idx] = s;
    }
}

// ---------------- axis-0 softmax stats, stage 1: coalesced chunk partials ----------------
__global__ __launch_bounds__(256) void colstat1(
    const float* __restrict__ rst, float* __restrict__ pm,
    float* __restrict__ psum, int N)
{
    const int blk = blockIdx.x;
    const int per = (N + CSCHUNK - 1) / CSCHUNK;
    const int lo = blk * per;
    const int hi = min(lo + per, N);
    const int c = threadIdx.x & 127, half = threadIdx.x >> 7;
    __shared__ float red[256];
    __shared__ float cmx[128];
    float m = -INFINITY;
    for (int r = lo + half; r < hi; r += 2)
        m = fmaxf(m, rst[(size_t)r * 128 + c]);
    red[threadIdx.x] = m;
    __syncthreads();
    if (threadIdx.x < 128)
        cmx[threadIdx.x] = fmaxf(red[threadIdx.x], red[threadIdx.x + 128]);
    __syncthreads();
    const float mm = cmx[c];
    float s = 0.f;
    for (int r = lo + half; r < hi; r += 2)
        s += __expf(rst[(size_t)r * 128 + c] - mm);
    red[threadIdx.x] = s;
    __syncthreads();
    if (threadIdx.x < 128) {
        pm[blk * 128 + threadIdx.x] = cmx[threadIdx.x];
        psum[blk * 128 + threadIdx.x] = red[threadIdx.x] + red[threadIdx.x + 128];
    }
}

// ---------------- axis-0 softmax stats, stage 2: combine chunk partials ----------------
__global__ __launch_bounds__(128) void colstat2(
    const float* __restrict__ pm, const float* __restrict__ psum,
    float* __restrict__ colmax, float* __restrict__ colsum)
{
    const int c = threadIdx.x;
    float m = -INFINITY;
    for (int b = 0; b < CSCHUNK; ++b) m = fmaxf(m, pm[b * 128 + c]);
    float s = 0.f;
    for (int b = 0; b < CSCHUNK; ++b) s += psum[b * 128 + c] * __expf(pm[b * 128 + c] - m);
    colmax[c] = m; colsum[c] = s;
}

// ---------------- softmax + folded classifier ----------------
__global__ __launch_bounds__(256) void final_kernel(
    const float* __restrict__ rst, const float* __restrict__ colmax,
    const float* __restrict__ colsum, const float* __restrict__ W1,
    const float* __restrict__ b1, const float* __restrict__ W2,
    const float* __restrict__ b2, float* __restrict__ out, int N)
{
    __shared__ float M[2][OUTD];
    __shared__ float bv[2];
    __shared__ float cm[128], cs[128];
    const int tid = threadIdx.x;
    if (tid < 64) {
        const int r = tid >> 5, o = tid & 31;
        float s = 0.f;
        #pragma unroll
        for (int k = 0; k < 16; ++k) s = fmaf(W2[r * 16 + k], W1[k * 32 + o], s);
        M[r][o] = s;
    }
    if (tid < 2) {
        float s = b2[tid];
        #pragma unroll
        for (int k = 0; k < 16; ++k) s = fmaf(b1[k], W2[tid * 16 + k], s);
        bv[tid] = s;
    }
    if (tid < 128) { cm[tid] = colmax[tid]; cs[tid] = colsum[tid]; }
    __syncthreads();
    for (int row = blockIdx.x * 256 + tid; row < N * 4; row += gridDim.x * 256) {
        const int n = row >> 2, h = row & 3;
        const float* r = rst + (size_t)n * 128 + h * 32;
        float a0 = bv[0], a1 = bv[1];
        #pragma unroll 4
        for (int o = 0; o < OUTD; ++o) {
            const int c = h * 32 + o;
            float p = __expf(r[o] - cm[c]) / cs[c];
            a0 = fmaf(p, M[0][o], a0);
            a1 = fmaf(p, M[1][o], a1);
        }
        out[(size_t)row * 2 + 0] = a0;
        out[(size_t)row * 2 + 1] = a1;
    }
}

extern "C" void kernel_launch(void* const* d_in, const int* in_sizes, int n_in,
                              void* d_out, int out_size, void* d_ws, size_t ws_size,
                              hipStream_t stream) {
    const float* ast_x   = (const float*)d_in[0];
    const float* c_init  = (const float*)d_in[1];
    const float* cfg_type= (const float*)d_in[2];
    const float* W_iou   = (const float*)d_in[3];
    const float* b_iou   = (const float*)d_in[4];
    const float* U_iou   = (const float*)d_in[5];
    const float* U_f_W   = (const float*)d_in[6];
    const float* U_f_b   = (const float*)d_in[7];
    const float* Wt      = (const float*)d_in[8];
    const float* Wfc     = (const float*)d_in[9];
    const float* attn_l  = (const float*)d_in[10];
    const float* attn_r  = (const float*)d_in[11];
    const float* W_out   = (const float*)d_in[12];
    const float* bias_g  = (const float*)d_in[13];
    const float* W1      = (const float*)d_in[14];
    const float* b1      = (const float*)d_in[15];
    const float* W2      = (const float*)d_in[16];
    const float* b2      = (const float*)d_in[17];
    const int* edge_src  = (const int*)d_in[18];
    const int* edge_dst  = (const int*)d_in[19];

    const int N = in_sizes[2] / XD;      // 20000
    const int E = in_sizes[18];          // 640000
    (void)n_in; (void)out_size; (void)ws_size;

    char* w = (char*)d_ws;
    auto take = [&](size_t bytes) { char* p = w; w += (bytes + 255) & ~(size_t)255; return p; };
    float*    h_root  = (float*)take((size_t)N * HD * 4);
    float*    el      = (float*)take((size_t)N * NHEADS * 4);
    float*    er      = (float*)take((size_t)N * NHEADS * 4);
    int*      cnt     = (int*)take((size_t)N * 4);
    int*      offs    = (int*)take(((size_t)N + 1) * 4);
    int*      cursor  = (int*)take((size_t)N * 4);
    int*      csr_src = (int*)take((size_t)E * 4);
    float*    rst     = (float*)take((size_t)N * 128 * 4);
    float*    colmax  = (float*)take(128 * 4);
    float*    colsum  = (float*)take(128 * 4);
    ushort_t* Wb_iou  = (ushort_t*)take(24576 * 2);
    ushort_t* Wb_f    = (ushort_t*)take(4096 * 2);
    ushort_t* Wb_u    = (ushort_t*)take(12288 * 2);
    float*    B_lr    = (float*)take(800 * 4);
    float*    pm      = (float*)take((size_t)CSCHUNK * 128 * 4);
    float*    psum    = (float*)take((size_t)CSCHUNK * 128 * 4);

    const int zeroBlocks = (N + 255) / 256;
    setup_kernel<<<161 + zeroBlocks, 256, 0, stream>>>(
        W_iou, U_f_W, U_iou, Wt, Wfc, attn_l, attn_r,
        Wb_iou, Wb_f, Wb_u, B_lr, cnt, N);
    count_kernel<<<1024, 256, 0, stream>>>(edge_dst, cnt, E);
    scan_kernel<<<1, 1024, 0, stream>>>(cnt, offs, cursor, N);
    fill_kernel<<<1024, 256, 0, stream>>>(edge_src, edge_dst, cursor, csr_src, E);
    treelstm_fused<<<(N + TPB - 1) / TPB, 256, 0, stream>>>(
        ast_x, c_init, Wb_iou, Wb_f, Wb_u, b_iou, U_f_b, h_root, N);
    elr_kernel<<<(N + 63) / 64, 256, 0, stream>>>(cfg_type, B_lr, el, er, N);
    agg_kernel<<<(N + 3) / 4, 256, 0, stream>>>(h_root, el, er, offs, csr_src, W_out, bias_g, rst, N);
    colstat1<<<CSCHUNK, 256, 0, stream>>>(rst, pm, psum, N);
    colstat2<<<1, 128, 0, stream>>>(pm, psum, colmax, colsum);
    final_kernel<<<(N * 4 + 255) / 256, 256, 0, stream>>>(rst, colmax, colsum, W1, b1, W2, b2, (float*)d_out, N);
}

// Round 6
// 288.167 us; speedup vs baseline: 13.6070x; 1.1966x over previous
//
#include <hip/hip_runtime.h>
#include <hip/hip_bf16.h>
#include <math.h>

#define XD 100
#define HD 64
#define GD 192
#define TL 15
#define NHEADS 4
#define OUTD 32
#define TPB 8        // trees per treelstm block
#define CSCHUNK 160  // colstat stage-1 blocks

typedef unsigned short ushort_t;
typedef unsigned int uint_t;
typedef __attribute__((ext_vector_type(8))) short bf16x8;
typedef __attribute__((ext_vector_type(4))) float f32x4;

__device__ __forceinline__ ushort_t f2bf(float x) {
    __hip_bfloat16 h = __float2bfloat16(x);
    return *reinterpret_cast<ushort_t*>(&h);
}
__device__ __forceinline__ float bf2f(ushort_t u) {
    unsigned int v = ((unsigned int)u) << 16;
    return __uint_as_float(v);
}
__device__ __forceinline__ float fsig(float x) {
    return __builtin_amdgcn_rcpf(1.0f + __expf(-x));
}
__device__ __forceinline__ float ftanh(float x) {
    float e = __expf(-2.0f * fabsf(x));
    float t = 1.0f - 2.0f * e * __builtin_amdgcn_rcpf(1.0f + e);
    return copysignf(t, x);
}
__device__ __forceinline__ bf16x8 pack8(float4 lo, float4 hi) {
    bf16x8 a;
    a[0] = (short)f2bf(lo.x); a[1] = (short)f2bf(lo.y);
    a[2] = (short)f2bf(lo.z); a[3] = (short)f2bf(lo.w);
    a[4] = (short)f2bf(hi.x); a[5] = (short)f2bf(hi.y);
    a[6] = (short)f2bf(hi.z); a[7] = (short)f2bf(hi.w);
    return a;
}
// raw barrier: LDS handoff only, NO vmcnt drain (prefetch loads stay in flight)
__device__ __forceinline__ void wave_barrier() {
    asm volatile("s_waitcnt lgkmcnt(0)" ::: "memory");
    __builtin_amdgcn_s_barrier();
}

struct XBank { float4 g0, g1; };

// ---------------- setup: weight packing + attn folding + W_out transpose + cnt zeroing ----------------
// B-frag for mfma_f32_16x16x32_bf16: lane l holds B[k=(l>>4)*8+j][n0+(l&15)], j=0..7
__global__ __launch_bounds__(256) void setup_kernel(
    const float* __restrict__ W_iou, const float* __restrict__ U_f_W,
    const float* __restrict__ U_iou, const float* __restrict__ Wt,
    const float* __restrict__ Wfc, const float* __restrict__ attn_l,
    const float* __restrict__ attn_r, const float* __restrict__ W_out,
    ushort_t* __restrict__ Wb_iou, ushort_t* __restrict__ Wb_f,
    ushort_t* __restrict__ Wb_u, float* __restrict__ B_lr,
    float* __restrict__ W_out_T, int* __restrict__ cnt, int N)
{
    __shared__ float A_s[8][HD];
    const int blk = blockIdx.x;
    const int tid = threadIdx.x;
    if (blk < 160) {
        int idx = blk * 256 + tid;               // [0, 40960)
        if (idx < 24576) {                       // W_iou: 4kt x 12nt
            int j = idx & 7, l = (idx >> 3) & 63, f = idx >> 9;
            int kt = f / 12, nt = f % 12;
            int k = kt * 32 + ((l >> 4) * 8) + j;
            int nn = nt * 16 + (l & 15);
            float v = (k < XD) ? W_iou[nn * XD + k] : 0.f;
            Wb_iou[idx] = f2bf(v);
        } else if (idx < 24576 + 4096) {         // U_f_W: 2kt x 4nt
            int t = idx - 24576;
            int j = t & 7, l = (t >> 3) & 63, f = t >> 9;
            int kt = f >> 2, nt = f & 3;
            int k = kt * 32 + ((l >> 4) * 8) + j;
            int nn = nt * 16 + (l & 15);
            Wb_f[t] = f2bf(U_f_W[nn * HD + k]);
        } else {                                  // U_iou: 2kt x 12nt
            int t = idx - 24576 - 4096;
            int j = t & 7, l = (t >> 3) & 63, f = t >> 9;
            int kt = f / 12, nt = f % 12;
            int k = kt * 32 + ((l >> 4) * 8) + j;
            int g = nt * 16 + (l & 15);
            Wb_u[t] = f2bf(U_iou[g * HD + k]);
        }
    } else if (blk == 160) {
        // fold attn into projection: B_lr[q][x], q=0..3 -> el, 4..7 -> er
        for (int o = tid; o < 8 * HD; o += 256) {
            int q = o >> 6, c = o & 63;
            int h = q & 3;
            const float* attn = (q < 4) ? attn_l : attn_r;
            float s = 0.f;
            #pragma unroll 4
            for (int oo = 0; oo < OUTD; ++oo)
                s = fmaf(attn[h * OUTD + oo], Wfc[(h * OUTD + oo) * HD + c], s);
            A_s[q][c] = s;
        }
        __syncthreads();
        for (int o = tid; o < 8 * XD; o += 256) {
            int q = o / XD, x = o - q * XD;
            float s = 0.f;
            #pragma unroll 4
            for (int c = 0; c < HD; ++c)
                s = fmaf(A_s[q][c], Wt[c * XD + x], s);
            B_lr[o] = s;
        }
        for (int idx = tid; idx < HD * OUTD; idx += 256) {
            int c = idx >> 5, o = idx & 31;
            W_out_T[idx] = W_out[o * HD + c];
        }
    } else {
        int i = (blk - 161) * 256 + tid;
        if (i < N) cnt[i] = 0;
    }
}

// ---------------- TreeLSTM fused: 2-deep prefetch, raw barriers, bf16 h_root out ----------------
__global__ __launch_bounds__(256) void treelstm_fused(
    const float* __restrict__ ast_x, const float* __restrict__ c_init,
    const ushort_t* __restrict__ Wb_iou, const ushort_t* __restrict__ Wb_f,
    const ushort_t* __restrict__ Wb_u, const float* __restrict__ b_iou,
    const float* __restrict__ U_f_b, ushort_t* __restrict__ h_rootb, int Ntrees)
{
    __shared__ __align__(16) ushort_t xsb[2][16][136];  // bf16 X, double-buffered
    __shared__ __align__(16) ushort_t hlb[2][16][72];   // bf16 h_leaf, double-buffered
    __shared__ __align__(16) ushort_t htb[16][72];      // bf16 h_tild (rows TPB..15 zero)
    __shared__ float credb[TPB][68];                    // f32 c_red per tree

    const int tid = threadIdx.x;
    const int lane = tid & 63;
    const int w = tid >> 6;
    const int arow = lane & 15;
    const int kgrp = lane >> 4;
    const int h = w * 16 + arow;
    const int base = blockIdx.x * TPB;

    const float bi = b_iou[h], bo = b_iou[64 + h], bu = b_iou[128 + h];
    const float fb = U_f_b[h];

    // persistent B fragments
    bf16x8 Bl[12];
    #pragma unroll
    for (int kt = 0; kt < 4; ++kt)
        #pragma unroll
        for (int j = 0; j < 3; ++j)
            Bl[kt * 3 + j] = *(const bf16x8*)(Wb_iou + (((size_t)kt * 12 + (w + 4 * j)) * 64 + lane) * 8);
    bf16x8 Bf[2];
    #pragma unroll
    for (int kt = 0; kt < 2; ++kt)
        Bf[kt] = *(const bf16x8*)(Wb_f + (((size_t)kt * 4 + w) * 64 + lane) * 8);

    // staging mapping: thread -> (row sr, 8-col chunk sc)
    const int sr = tid >> 4;
    const int sc = tid & 15;
    const bool sactive = (sr < TL) && (sc < 13);

    // zero-fill pads: xsb cols 104..127 + row 15 (both buffers); htb rows TPB..15
    for (int b = 0; b < 2; ++b) {
        for (int i = tid; i < 16 * 24; i += 256) {
            int r = i / 24, rem = i - r * 24;
            xsb[b][r][104 + rem] = 0;
        }
        for (int i = tid; i < 104; i += 256) xsb[b][15][i] = 0;
    }
    for (int i = tid; i < (16 - TPB) * 72; i += 256)
        htb[TPB + i / 72][i % 72] = 0;

    auto load_x = [&](int n, XBank& bk) {
        bk.g0 = make_float4(0.f, 0.f, 0.f, 0.f);
        bk.g1 = make_float4(0.f, 0.f, 0.f, 0.f);
        if (sactive && n < Ntrees) {
            const float* xrow = ast_x + ((size_t)n * 16 + 1 + sr) * XD + sc * 8;
            bk.g0 = *(const float4*)xrow;
            if (sc < 12) bk.g1 = *(const float4*)(xrow + 4);
        }
    };
    auto load_c = [&](int n, float (&cb)[4]) {
        const float* cbp = c_init + ((size_t)n * 16 + 1) * HD;
        #pragma unroll
        for (int r = 0; r < 4; ++r) {
            int t = kgrp * 4 + r;
            cb[r] = (t < TL && n < Ntrees) ? cbp[t * HD + h] : 0.f;
        }
    };

    XBank bankA, bankB;
    float cbA[4], cbB[4];
    // prologue: T0 -> bankA/cbA, T1 -> bankB/cbB; stage T0
    load_x(base + 0, bankA);
    load_c(base + 0, cbA);
    load_x(base + 1, bankB);
    load_c(base + 1, cbB);
    if (sactive) *(bf16x8*)&xsb[0][sr][sc * 8] = pack8(bankA.g0, bankA.g1);
    wave_barrier();

    // iteration body: parity p = tt&1; stage = bank holding tree tt+1; load = freed bank (tree tt+2)
    auto body = [&](int tt, XBank& stage_b, XBank& load_b, float (&cb)[4]) {
        const int p = tt & 1;
        // stage tree tt+1 (its loads issued >= 1 full iteration ago -> latency hidden)
        if (tt + 1 < TPB && sactive)
            *(bf16x8*)&xsb[p ^ 1][sr][sc * 8] = pack8(stage_b.g0, stage_b.g1);
        // issue tree tt+2 X loads (stay in flight across the raw barrier)
        if (tt + 2 < TPB) load_x(base + tt + 2, load_b);

        // leaf GEMM from xsb[p]
        f32x4 a0 = {0,0,0,0}, a1 = {0,0,0,0}, a2 = {0,0,0,0};
        #pragma unroll
        for (int kt = 0; kt < 4; ++kt) {
            bf16x8 a = *(const bf16x8*)&xsb[p][arow][kt * 32 + kgrp * 8];
            a0 = __builtin_amdgcn_mfma_f32_16x16x32_bf16(a, Bl[kt * 3 + 0], a0, 0, 0, 0);
            a1 = __builtin_amdgcn_mfma_f32_16x16x32_bf16(a, Bl[kt * 3 + 1], a1, 0, 0, 0);
            a2 = __builtin_amdgcn_mfma_f32_16x16x32_bf16(a, Bl[kt * 3 + 2], a2, 0, 0, 0);
        }

        // leaf elementwise in registers; bf16 h_leaf -> hlb[p]
        float cl[4];
        float hsum = 0.f;
        #pragma unroll
        for (int r = 0; r < 4; ++r) {
            int t = kgrp * 4 + r;
            float hl = 0.f, c = 0.f;
            if (t < TL) {
                float i_ = a0[r] + bi, o_ = a1[r] + bo, u_ = a2[r] + bu;
                c = fsig(i_) * ftanh(u_) + cb[r];
                hl = fsig(o_) * ftanh(c);
            }
            cl[r] = c;
            hsum += hl;
            hlb[p][t][h] = f2bf(hl);
        }
        // issue tree tt+2 c_init loads (cb just consumed)
        if (tt + 2 < TPB) load_c(base + tt + 2, cb);

        wave_barrier();   // hlb[p] + xsb[p^1] visible; vmem stays in flight

        // forget GEMM (F fragment layout == c_leaf register layout)
        f32x4 fa = {0,0,0,0};
        #pragma unroll
        for (int kt = 0; kt < 2; ++kt) {
            bf16x8 a = *(const bf16x8*)&hlb[p][arow][kt * 32 + kgrp * 8];
            fa = __builtin_amdgcn_mfma_f32_16x16x32_bf16(a, Bf[kt], fa, 0, 0, 0);
        }
        float credsum = 0.f;
        #pragma unroll
        for (int r = 0; r < 4; ++r) {
            int t = kgrp * 4 + r;
            if (t < TL) credsum += fsig(fa[r] + fb) * cl[r];
        }
        hsum += __shfl_xor(hsum, 16);       hsum += __shfl_xor(hsum, 32);
        credsum += __shfl_xor(credsum, 16); credsum += __shfl_xor(credsum, 32);
        if (kgrp == 0) {
            htb[tt][h] = f2bf(hsum);
            credb[tt][h] = credsum;
        }
    };

    for (int tt = 0; tt < TPB; tt += 2) {
        body(tt,     bankB, bankA, cbA);
        body(tt + 1, bankA, bankB, cbB);
    }
    wave_barrier();   // htb/credb complete

    // root GEMM: [16,64] @ [64,192] (rows TPB..15 zero)
    f32x4 r0 = {0,0,0,0}, r1 = {0,0,0,0}, r2 = {0,0,0,0};
    #pragma unroll
    for (int kt = 0; kt < 2; ++kt) {
        bf16x8 a = *(const bf16x8*)&htb[arow][kt * 32 + kgrp * 8];
        bf16x8 b0 = *(const bf16x8*)(Wb_u + (((size_t)kt * 12 + w)     * 64 + lane) * 8);
        bf16x8 b1 = *(const bf16x8*)(Wb_u + (((size_t)kt * 12 + w + 4) * 64 + lane) * 8);
        bf16x8 b2 = *(const bf16x8*)(Wb_u + (((size_t)kt * 12 + w + 8) * 64 + lane) * 8);
        r0 = __builtin_amdgcn_mfma_f32_16x16x32_bf16(a, b0, r0, 0, 0, 0);
        r1 = __builtin_amdgcn_mfma_f32_16x16x32_bf16(a, b1, r1, 0, 0, 0);
        r2 = __builtin_amdgcn_mfma_f32_16x16x32_bf16(a, b2, r2, 0, 0, 0);
    }
    #pragma unroll
    for (int r = 0; r < 4; ++r) {
        int m = kgrp * 4 + r;   // tree index within block
        if (m < TPB && base + m < Ntrees) {
            float c = fsig(r0[r] + bi) * ftanh(r2[r] + bu) + credb[m][h];
            h_rootb[(size_t)(base + m) * HD + h] = f2bf(fsig(r1[r] + bo) * ftanh(c));
        }
    }
}

// ---------------- el/er via folded projection ----------------
__global__ __launch_bounds__(256) void elr_kernel(
    const float* __restrict__ cfg_type, const float* __restrict__ B_lr,
    float* __restrict__ el, float* __restrict__ er, int N)
{
    __shared__ float xs[64 * XD];
    __shared__ float Bs[8 * XD];
    const int tid = threadIdx.x;
    const int base = blockIdx.x * 64;
    for (int i = tid; i < 8 * XD; i += 256) Bs[i] = B_lr[i];
    const size_t goff = (size_t)base * XD;
    long lim = (long)N * XD - (long)goff;
    if (lim > 64 * XD) lim = 64 * XD;
    for (int i = tid; i < lim; i += 256) xs[i] = cfg_type[goff + i];
    __syncthreads();
    for (int o = tid; o < 512; o += 256) {
        int r = o >> 3, q = o & 7;
        int node = base + r;
        if (node < N) {
            float s = 0.f;
            #pragma unroll 4
            for (int k = 0; k < XD; ++k)
                s = fmaf(xs[r * XD + k], Bs[q * XD + k], s);
            ((q < 4) ? el : er)[(size_t)node * NHEADS + (q & 3)] = s;
        }
    }
}

// ---------------- CSR build ----------------
__global__ void count_kernel(const int* __restrict__ dst, int* __restrict__ cnt, int E) {
    for (int e = blockIdx.x * blockDim.x + threadIdx.x; e < E; e += gridDim.x * blockDim.x)
        atomicAdd(&cnt[dst[e]], 1);
}

__global__ __launch_bounds__(1024) void scan_kernel(
    const int* __restrict__ cnt, int* __restrict__ offs, int* __restrict__ cursor, int N)
{
    __shared__ int part[1024];
    const int tid = threadIdx.x;
    const int per = (N + 1023) >> 10;
    int begin = tid * per;
    int end = begin + per; if (end > N) end = N;
    int s = 0;
    for (int i = begin; i < end && i < N; ++i) s += cnt[i];
    part[tid] = s;
    __syncthreads();
    for (int off = 1; off < 1024; off <<= 1) {
        int t = (tid >= off) ? part[tid - off] : 0;
        __syncthreads();
        part[tid] += t;
        __syncthreads();
    }
    int run = part[tid] - s;
    for (int i = begin; i < end && i < N; ++i) {
        offs[i] = run; cursor[i] = run; run += cnt[i];
    }
    if (tid == 1023) offs[N] = part[1023];
}

__global__ void fill_kernel(const int* __restrict__ src, const int* __restrict__ dst,
                            int* __restrict__ cursor, int* __restrict__ csr_src, int E) {
    for (int e = blockIdx.x * blockDim.x + threadIdx.x; e < E; e += gridDim.x * blockDim.x) {
        int p = atomicAdd(&cursor[dst[e]], 1);
        csr_src[p] = src[e];
    }
}

// ---------------- per-dst edge softmax + aggregation + W_out: 1 wave per dst ----------------
// No max-subtraction (|leaky(el+er)| bounded ~1); src/ez broadcast via __shfl (no LDS
// pointer-chase); 2 edges per trip (bf16 h_root rows: 32 lanes x uint = 2 channels/lane).
__global__ __launch_bounds__(256) void agg_kernel(
    const ushort_t* __restrict__ h_rootb, const float* __restrict__ el,
    const float* __restrict__ er, const int* __restrict__ offs,
    const int* __restrict__ csr_src, const float* __restrict__ W_out_T,
    const float* __restrict__ bias_g, float* __restrict__ rst, int N)
{
    const int wid = threadIdx.x >> 6;
    const int lane = threadIdx.x & 63;
    const int n = blockIdx.x * 4 + wid;
    if (n >= N) return;
    __shared__ __align__(8) float s_agg[4][NHEADS][HD];

    const int beg = offs[n];
    const int deg = offs[n + 1] - beg;
    const float4 erv = *(const float4*)&er[(size_t)n * NHEADS];
    const uint_t* hb = (const uint_t*)h_rootb;
    const int cp = lane & 31;     // channel pair
    const int half = lane >> 5;   // edge slot within trip

    float2 acc[NHEADS] = {{0.f,0.f},{0.f,0.f},{0.f,0.f},{0.f,0.f}};
    float ps[NHEADS] = {0.f, 0.f, 0.f, 0.f};

    for (int c0 = 0; c0 < deg; c0 += 64) {
        const int j = c0 + lane;
        int srcv = 0;
        float ez0 = 0.f, ez1 = 0.f, ez2 = 0.f, ez3 = 0.f;
        if (j < deg) {
            srcv = csr_src[beg + j];
            float4 elv = *(const float4*)&el[(size_t)srcv * NHEADS];
            float t0 = elv.x + erv.x, t1 = elv.y + erv.y;
            float t2 = elv.z + erv.z, t3 = elv.w + erv.w;
            t0 = t0 > 0.f ? t0 : 0.2f * t0;
            t1 = t1 > 0.f ? t1 : 0.2f * t1;
            t2 = t2 > 0.f ? t2 : 0.2f * t2;
            t3 = t3 > 0.f ? t3 : 0.2f * t3;
            ez0 = __expf(t0); ez1 = __expf(t1);
            ez2 = __expf(t2); ez3 = __expf(t3);
            ps[0] += ez0; ps[1] += ez1; ps[2] += ez2; ps[3] += ez3;
        }
        const int cnt2 = min(64, deg - c0);
        #pragma unroll 8
        for (int j0 = 0; j0 < cnt2; j0 += 2) {
            const int sidx = j0 + half;           // slot beyond cnt2 has ez==0 -> contributes 0
            const int sj = __shfl(srcv, sidx);
            const float e0 = __shfl(ez0, sidx);
            const float e1 = __shfl(ez1, sidx);
            const float e2 = __shfl(ez2, sidx);
            const float e3 = __shfl(ez3, sidx);
            const uint_t hv = hb[(size_t)sj * 32 + cp];
            const float h0 = bf2f((ushort_t)(hv & 0xffffu));
            const float h1 = bf2f((ushort_t)(hv >> 16));
            acc[0].x = fmaf(e0, h0, acc[0].x); acc[0].y = fmaf(e0, h1, acc[0].y);
            acc[1].x = fmaf(e1, h0, acc[1].x); acc[1].y = fmaf(e1, h1, acc[1].y);
            acc[2].x = fmaf(e2, h0, acc[2].x); acc[2].y = fmaf(e2, h1, acc[2].y);
            acc[3].x = fmaf(e3, h0, acc[3].x); acc[3].y = fmaf(e3, h1, acc[3].y);
        }
    }

    #pragma unroll
    for (int hh = 0; hh < NHEADS; ++hh)
        for (int off = 1; off < 64; off <<= 1)
            ps[hh] += __shfl_xor(ps[hh], off);
    // combine the two edge-slot halves (same channel pair)
    #pragma unroll
    for (int hh = 0; hh < NHEADS; ++hh) {
        acc[hh].x += __shfl_xor(acc[hh].x, 32);
        acc[hh].y += __shfl_xor(acc[hh].y, 32);
    }

    if (half == 0) {
        #pragma unroll
        for (int hh = 0; hh < NHEADS; ++hh) {
            float inv = (deg > 0) ? 1.f / ps[hh] : 0.f;
            *(float2*)&s_agg[wid][hh][2 * cp] = make_float2(acc[hh].x * inv, acc[hh].y * inv);
        }
    }
    // same-wave producer/consumer: compiler lgkmcnt ordering suffices (no barrier)
    #pragma unroll
    for (int t = 0; t < 2; ++t) {
        const int idx = t * 64 + lane;           // 0..127
        const int hh = idx >> 5, o = idx & 31;
        float s = bias_g[idx];
        #pragma unroll 8
        for (int c = 0; c < HD; ++c)
            s = fmaf(s_agg[wid][hh][c], W_out_T[c * OUTD + o], s);
        rst[(size_t)n * 128 + idx] = s;
    }
}

// ---------------- axis-0 softmax stats, stage 1: coalesced chunk partials ----------------
__global__ __launch_bounds__(256) void colstat1(
    const float* __restrict__ rst, float* __restrict__ pm,
    float* __restrict__ psum, int N)
{
    const int blk = blockIdx.x;
    const int per = (N + CSCHUNK - 1) / CSCHUNK;
    const int lo = blk * per;
    const int hi = min(lo + per, N);
    const int c = threadIdx.x & 127, half = threadIdx.x >> 7;
    __shared__ float red[256];
    __shared__ float cmx[128];
    float m = -INFINITY;
    for (int r = lo + half; r < hi; r += 2)
        m = fmaxf(m, rst[(size_t)r * 128 + c]);
    red[threadIdx.x] = m;
    __syncthreads();
    if (threadIdx.x < 128)
        cmx[threadIdx.x] = fmaxf(red[threadIdx.x], red[threadIdx.x + 128]);
    __syncthreads();
    const float mm = cmx[c];
    float s = 0.f;
    for (int r = lo + half; r < hi; r += 2)
        s += __expf(rst[(size_t)r * 128 + c] - mm);
    red[threadIdx.x] = s;
    __syncthreads();
    if (threadIdx.x < 128) {
        pm[blk * 128 + threadIdx.x] = cmx[threadIdx.x];
        psum[blk * 128 + threadIdx.x] = red[threadIdx.x] + red[threadIdx.x + 128];
    }
}

// ---------------- axis-0 softmax stats, stage 2: combine chunk partials ----------------
__global__ __launch_bounds__(128) void colstat2(
    const float* __restrict__ pm, const float* __restrict__ psum,
    float* __restrict__ colmax, float* __restrict__ colsum)
{
    const int c = threadIdx.x;
    float m = -INFINITY;
    for (int b = 0; b < CSCHUNK; ++b) m = fmaxf(m, pm[b * 128 + c]);
    float s = 0.f;
    for (int b = 0; b < CSCHUNK; ++b) s += psum[b * 128 + c] * __expf(pm[b * 128 + c] - m);
    colmax[c] = m; colsum[c] = s;
}

// ---------------- softmax + folded classifier ----------------
__global__ __launch_bounds__(256) void final_kernel(
    const float* __restrict__ rst, const float* __restrict__ colmax,
    const float* __restrict__ colsum, const float* __restrict__ W1,
    const float* __restrict__ b1, const float* __restrict__ W2,
    const float* __restrict__ b2, float* __restrict__ out, int N)
{
    __shared__ float M[2][OUTD];
    __shared__ float bv[2];
    __shared__ float cm[128], cs[128];
    const int tid = threadIdx.x;
    if (tid < 64) {
        const int r = tid >> 5, o = tid & 31;
        float s = 0.f;
        #pragma unroll
        for (int k = 0; k < 16; ++k) s = fmaf(W2[r * 16 + k], W1[k * 32 + o], s);
        M[r][o] = s;
    }
    if (tid < 2) {
        float s = b2[tid];
        #pragma unroll
        for (int k = 0; k < 16; ++k) s = fmaf(b1[k], W2[tid * 16 + k], s);
        bv[tid] = s;
    }
    if (tid < 128) { cm[tid] = colmax[tid]; cs[tid] = colsum[tid]; }
    __syncthreads();
    for (int row = blockIdx.x * 256 + tid; row < N * 4; row += gridDim.x * 256) {
        const int n = row >> 2, h = row & 3;
        const float* r = rst + (size_t)n * 128 + h * 32;
        float a0 = bv[0], a1 = bv[1];
        #pragma unroll 4
        for (int o = 0; o < OUTD; ++o) {
            const int c = h * 32 + o;
            float p = __expf(r[o] - cm[c]) / cs[c];
            a0 = fmaf(p, M[0][o], a0);
            a1 = fmaf(p, M[1][o], a1);
        }
        out[(size_t)row * 2 + 0] = a0;
        out[(size_t)row * 2 + 1] = a1;
    }
}

extern "C" void kernel_launch(void* const* d_in, const int* in_sizes, int n_in,
                              void* d_out, int out_size, void* d_ws, size_t ws_size,
                              hipStream_t stream) {
    const float* ast_x   = (const float*)d_in[0];
    const float* c_init  = (const float*)d_in[1];
    const float* cfg_type= (const float*)d_in[2];
    const float* W_iou   = (const float*)d_in[3];
    const float* b_iou   = (const float*)d_in[4];
    const float* U_iou   = (const float*)d_in[5];
    const float* U_f_W   = (const float*)d_in[6];
    const float* U_f_b   = (const float*)d_in[7];
    const float* Wt      = (const float*)d_in[8];
    const float* Wfc     = (const float*)d_in[9];
    const float* attn_l  = (const float*)d_in[10];
    const float* attn_r  = (const float*)d_in[11];
    const float* W_out   = (const float*)d_in[12];
    const float* bias_g  = (const float*)d_in[13];
    const float* W1      = (const float*)d_in[14];
    const float* b1      = (const float*)d_in[15];
    const float* W2      = (const float*)d_in[16];
    const float* b2      = (const float*)d_in[17];
    const int* edge_src  = (const int*)d_in[18];
    const int* edge_dst  = (const int*)d_in[19];

    const int N = in_sizes[2] / XD;      // 20000
    const int E = in_sizes[18];          // 640000
    (void)n_in; (void)out_size; (void)ws_size;

    char* w = (char*)d_ws;
    auto take = [&](size_t bytes) { char* p = w; w += (bytes + 255) & ~(size_t)255; return p; };
    ushort_t* h_rootb = (ushort_t*)take((size_t)N * HD * 2);
    float*    el      = (float*)take((size_t)N * NHEADS * 4);
    float*    er      = (float*)take((size_t)N * NHEADS * 4);
    int*      cnt     = (int*)take((size_t)N * 4);
    int*      offs    = (int*)take(((size_t)N + 1) * 4);
    int*      cursor  = (int*)take((size_t)N * 4);
    int*      csr_src = (int*)take((size_t)E * 4);
    float*    rst     = (float*)take((size_t)N * 128 * 4);
    float*    colmax  = (float*)take(128 * 4);
    float*    colsum  = (float*)take(128 * 4);
    ushort_t* Wb_iou  = (ushort_t*)take(24576 * 2);
    ushort_t* Wb_f    = (ushort_t*)take(4096 * 2);
    ushort_t* Wb_u    = (ushort_t*)take(12288 * 2);
    float*    B_lr    = (float*)take(800 * 4);
    float*    W_out_T = (float*)take((size_t)HD * OUTD * 4);
    float*    pm      = (float*)take((size_t)CSCHUNK * 128 * 4);
    float*    psum    = (float*)take((size_t)CSCHUNK * 128 * 4);

    const int zeroBlocks = (N + 255) / 256;
    setup_kernel<<<161 + zeroBlocks, 256, 0, stream>>>(
        W_iou, U_f_W, U_iou, Wt, Wfc, attn_l, attn_r, W_out,
        Wb_iou, Wb_f, Wb_u, B_lr, W_out_T, cnt, N);
    count_kernel<<<1024, 256, 0, stream>>>(edge_dst, cnt, E);
    scan_kernel<<<1, 1024, 0, stream>>>(cnt, offs, cursor, N);
    fill_kernel<<<1024, 256, 0, stream>>>(edge_src, edge_dst, cursor, csr_src, E);
    treelstm_fused<<<(N + TPB - 1) / TPB, 256, 0, stream>>>(
        ast_x, c_init, Wb_iou, Wb_f, Wb_u, b_iou, U_f_b, h_rootb, N);
    elr_kernel<<<(N + 63) / 64, 256, 0, stream>>>(cfg_type, B_lr, el, er, N);
    agg_kernel<<<(N + 3) / 4, 256, 0, stream>>>(h_rootb, el, er, offs, csr_src, W_out_T, bias_g, rst, N);
    colstat1<<<CSCHUNK, 256, 0, stream>>>(rst, pm, psum, N);
    colstat2<<<1, 128, 0, stream>>>(pm, psum, colmax, colsum);
    final_kernel<<<(N * 4 + 255) / 256, 256, 0, stream>>>(rst, colmax, colsum, W1, b1, W2, b2, (float*)d_out, N);
}